// Round 13
// baseline (186.450 us; speedup 1.0000x reference)
//
#include <hip/hip_runtime.h>
#include <hip/hip_bf16.h>
#include <cstdint>
#include <cstddef>

#define NN 100000
#define NE 1600000
#define FIN 128
#define HD 64
#define NC 40
#define NTILE (NN / 16)                      // 6250 MFMA row-tiles
#define MM_BLOCKS ((NTILE + 3) / 4)          // 1563

#define BUK 256                              // nodes per bucket
#define NBUK ((NN + BUK - 1) / BUK)          // 391
#define EPB 1024                             // edges per hist/scatter block
#define NBLK ((NE + EPB - 1) / EPB)          // 1563

#define XSTR 68                              // LDS row stride in u32 (64 data + 4 pad)

typedef unsigned short u16;
typedef unsigned int u32;
typedef __attribute__((ext_vector_type(8))) short short8v;
typedef __attribute__((ext_vector_type(4))) float accf4;

__device__ __forceinline__ float u2lo(u32 u) { return __uint_as_float(u << 16); }
__device__ __forceinline__ float u2hi(u32 u) { return __uint_as_float(u & 0xFFFF0000u); }
__device__ __forceinline__ u16 f2b(float f) {            // RNE f32->bf16
    u32 u = __float_as_uint(f);
    return (u16)((u + 0x7FFFu + ((u >> 16) & 1u)) >> 16);
}
__device__ __forceinline__ u32 pk2(float lo, float hi) {
    return (u32)f2b(lo) | ((u32)f2b(hi) << 16);
}

// ------- fused: per-block bucket histogram (LDS) || lin1 (LDS-staged x + MFMA) -------
__launch_bounds__(256)
__global__ void k_build1(const int* __restrict__ ei, u32* __restrict__ hist,
                         const float* __restrict__ x, const float* __restrict__ W,
                         const float* __restrict__ b, u16* __restrict__ out) {
    if (blockIdx.x < NBLK) {
        __shared__ u32 lh[NBUK];
        int blk = blockIdx.x, tid = threadIdx.x;
        for (int i = tid; i < NBUK; i += 256) lh[i] = 0;
        __syncthreads();
        #pragma unroll
        for (int it = 0; it < EPB / 256; it++) {
            int e = blk * EPB + it * 256 + tid;
            if (e < NE) {
                int col = ei[NE + e];
                atomicAdd(&lh[col >> 8], 1u);
            }
        }
        __syncthreads();
        for (int i = tid; i < NBUK; i += 256) hist[(size_t)i * NBLK + blk] = lh[i];
        return;
    }
    // ---- lin1 half: stage 64 x-rows as bf16 in LDS (coalesced), then MFMA ----
    __shared__ u32 xs[64 * XSTR];
    int tid = threadIdx.x;
    int bi  = blockIdx.x - NBLK;
    int nodeB = bi * 64;
    const float4* x4 = (const float4*)x;
    for (int idx = tid; idx < 64 * 16; idx += 256) {
        int row = idx >> 4, seg = idx & 15;
        uint4 d = make_uint4(0u, 0u, 0u, 0u);
        if (nodeB + row < NN) {
            float4 a = x4[(size_t)(nodeB + row) * 32 + seg * 2];
            float4 c = x4[(size_t)(nodeB + row) * 32 + seg * 2 + 1];
            d.x = pk2(a.x, a.y);
            d.y = pk2(a.z, a.w);
            d.z = pk2(c.x, c.y);
            d.w = pk2(c.z, c.w);
        }
        *(uint4*)(xs + row * XSTR + seg * 4) = d;
    }
    __syncthreads();
    int lane = tid & 63;
    int wv   = tid >> 6;
    int tile = bi * 4 + wv;
    if (tile >= NTILE) return;
    int row = lane & 15;
    int kg  = lane >> 4;
    short8v bW[4][4];
    #pragma unroll
    for (int kt = 0; kt < 4; kt++)
        #pragma unroll
        for (int ct = 0; ct < 4; ct++)
            #pragma unroll
            for (int j = 0; j < 8; j++)
                bW[kt][ct][j] = (short)f2b(W[(kt*32 + kg*8 + j) * HD + ct*16 + row]);
    int node0 = tile * 16;
    short8v af[4];
    #pragma unroll
    for (int kt = 0; kt < 4; kt++)
        af[kt] = *(const short8v*)(xs + (wv*16 + row) * XSTR + kt * 16 + kg * 4);
    accf4 acc[4] = {};
    #pragma unroll
    for (int kt = 0; kt < 4; kt++)
        #pragma unroll
        for (int ct = 0; ct < 4; ct++)
            acc[ct] = __builtin_amdgcn_mfma_f32_16x16x32_bf16(af[kt], bW[kt][ct], acc[ct], 0, 0, 0);
    #pragma unroll
    for (int ct = 0; ct < 4; ct++) {
        float bias = b[ct*16 + row];
        #pragma unroll
        for (int r = 0; r < 4; r++) {
            float v = fmaxf(acc[ct][r] + bias, 0.f);
            out[(size_t)(node0 + kg*4 + r) * HD + ct*16 + row] = f2b(v);
        }
    }
}

// per-bucket exclusive prefix over blocks (in place); total -> bucketTotal
__global__ void k_bscan(u32* __restrict__ hist, u32* __restrict__ bucketTotal) {
    int b = blockIdx.x;
    int lane = threadIdx.x;                  // 64 threads
    u32* h = hist + (size_t)b * NBLK;
    u32 carry = 0;
    for (int j0 = 0; j0 < NBLK; j0 += 64) {
        int j = j0 + lane;
        u32 v = (j < NBLK) ? h[j] : 0;
        u32 inc = v;
        #pragma unroll
        for (int d = 1; d < 64; d <<= 1) {
            u32 t = __shfl_up(inc, d);
            if (lane >= d) inc += t;
        }
        if (j < NBLK) h[j] = carry + inc - v;
        carry += __shfl(inc, 63);
    }
    if (lane == 0) bucketTotal[b] = carry;
}

// scan bucketTotal -> bucketStart (exclusive); bucketStart[NBUK]=NE; off[NN]=NE
__global__ void k_bstart(const u32* __restrict__ bucketTotal, u32* __restrict__ bucketStart,
                         int* __restrict__ off) {
    int lane = threadIdx.x;                  // 64 threads
    u32 carry = 0;
    for (int j0 = 0; j0 < NBUK; j0 += 64) {
        int j = j0 + lane;
        u32 v = (j < NBUK) ? bucketTotal[j] : 0;
        u32 inc = v;
        #pragma unroll
        for (int d = 1; d < 64; d <<= 1) {
            u32 t = __shfl_up(inc, d);
            if (lane >= d) inc += t;
        }
        if (j < NBUK) bucketStart[j] = carry + inc - v;
        carry += __shfl(inc, 63);
    }
    if (lane == 0) { bucketStart[NBUK] = carry; off[NN] = (int)carry; }
}

// scatter edges into bucket segments: rank via LDS atomics; one packed 8B record
// rec.x = row | (in-bucket col << 24), rec.y = raw ew bits
__launch_bounds__(256)
__global__ void k_scatter(const int* __restrict__ ei, const float* __restrict__ ew,
                          const u32* __restrict__ hist, const u32* __restrict__ bucketStart,
                          uint2* __restrict__ rec) {
    __shared__ u32 lh[NBUK];
    __shared__ u32 gb[NBUK];
    int blk = blockIdx.x, tid = threadIdx.x;
    for (int i = tid; i < NBUK; i += 256) {
        lh[i] = 0;
        gb[i] = bucketStart[i] + hist[(size_t)i * NBLK + blk];
    }
    __syncthreads();
    #pragma unroll
    for (int it = 0; it < EPB / 256; it++) {
        int e = blk * EPB + it * 256 + tid;
        if (e < NE) {
            int row = ei[e], col = ei[NE + e];
            float wv = ew[e];
            int bkt = col >> 8;
            u32 cl = (u32)(col & 255);
            u32 r = atomicAdd(&lh[bkt], 1u);
            u32 slot = gb[bkt] + r;
            rec[slot] = make_uint2((u32)row | (cl << 24), __float_as_uint(wv));
        }
    }
}

// per-bucket CSR build: packed LDS hist -> dinv, off, csr=(row, raw ew)
__launch_bounds__(256)
__global__ void k_bucket(const uint2* __restrict__ rec, const u32* __restrict__ bucketStart,
                         float* __restrict__ dinv, int* __restrict__ off,
                         uint2* __restrict__ csr) {
    __shared__ u32 lpk[BUK];
    __shared__ u32 loff[BUK];
    __shared__ u32 wt[4];
    int b = blockIdx.x, tid = threadIdx.x;
    int base = b * BUK;
    u32 seg0 = bucketStart[b], seg1 = bucketStart[b + 1];
    int nb = (int)(seg1 - seg0);
    lpk[tid] = 0;
    __syncthreads();
    for (int idx = tid; idx < nb; idx += 256) {
        uint2 ab = rec[seg0 + idx];
        u32 cl = ab.x >> 24;
        u32 fx = __float2uint_rn(__uint_as_float(ab.y) * 16384.0f);   // Q6.14
        atomicAdd(&lpk[cl], (1u << 20) | fx);
    }
    __syncthreads();
    u32 pk = lpk[tid];
    u32 cnt = pk >> 20;
    int node = base + tid;
    if (node < NN) dinv[node] = rsqrtf(1.0f + (float)(pk & 0xFFFFFu) * (1.0f / 16384.0f));
    // exclusive scan of cnt over 256
    int lane = tid & 63, wid = tid >> 6;
    u32 inc = cnt;
    #pragma unroll
    for (int d = 1; d < 64; d <<= 1) {
        u32 t = __shfl_up(inc, d);
        if (lane >= d) inc += t;
    }
    if (lane == 63) wt[wid] = inc;
    __syncthreads();
    u32 wof = 0;
    #pragma unroll
    for (int k = 0; k < 4; k++) if (k < wid) wof += wt[k];
    loff[tid] = wof + inc - cnt;
    if (node < NN) off[node] = (int)(seg0 + loff[tid]);
    lpk[tid] = 0;                    // reuse as rank counters
    __syncthreads();
    for (int idx = tid; idx < nb; idx += 256) {
        uint2 ab = rec[seg0 + idx];
        u32 cl = ab.x >> 24;
        u32 r2 = atomicAdd(&lpk[cl], 1u);
        csr[seg0 + loff[cl] + r2] = make_uint2(ab.x & 0xFFFFFFu, ab.y);   // (row, raw ew)
    }
}

// out(bf16) = dinv-scaled A(bf16) @ W: tbl'[r] = dinv[r] * (A@W)[r]
__launch_bounds__(256)
__global__ void k_mm64(const u16* __restrict__ A, const float* __restrict__ W,
                       const float* __restrict__ dinv, u16* __restrict__ out) {
    int lane = threadIdx.x & 63;
    int tile = blockIdx.x * 4 + (threadIdx.x >> 6);
    if (tile >= NTILE) return;
    int row = lane & 15;
    int kg  = lane >> 4;
    short8v bW[2][4];
    #pragma unroll
    for (int kt = 0; kt < 2; kt++)
        #pragma unroll
        for (int ct = 0; ct < 4; ct++)
            #pragma unroll
            for (int j = 0; j < 8; j++)
                bW[kt][ct][j] = (short)f2b(W[(kt*32 + kg*8 + j) * HD + ct*16 + row]);
    int node0 = tile * 16;
    const u16* ar = A + (size_t)(node0 + row) * HD + kg * 8;
    short8v af0 = *(const short8v*)(ar);
    short8v af1 = *(const short8v*)(ar + 32);
    accf4 acc[4] = {};
    #pragma unroll
    for (int ct = 0; ct < 4; ct++) {
        acc[ct] = __builtin_amdgcn_mfma_f32_16x16x32_bf16(af0, bW[0][ct], acc[ct], 0, 0, 0);
        acc[ct] = __builtin_amdgcn_mfma_f32_16x16x32_bf16(af1, bW[1][ct], acc[ct], 0, 0, 0);
    }
    float dr[4];
    #pragma unroll
    for (int r = 0; r < 4; r++) dr[r] = dinv[node0 + kg*4 + r];
    #pragma unroll
    for (int ct = 0; ct < 4; ct++)
        #pragma unroll
        for (int r = 0; r < 4; r++)
            out[(size_t)(node0 + kg*4 + r) * HD + ct*16 + row] = f2b(acc[ct][r] * dr[r]);
}

// out(bf16) = relu( dinv_c * (tbl'[c] + sum_e ew * tbl'[r]) + bias )
// 8 nodes/wave, 8 lanes/row, uint4 (8 bf16) per lane: 1 gather instr = 8 edges
__launch_bounds__(256)
__global__ void k_agg(const uint4* __restrict__ Bm4, const int* __restrict__ off,
                      const uint2* __restrict__ csr, const float* __restrict__ dinv,
                      const float* __restrict__ bias, uint4* __restrict__ outp) {
    int lane = threadIdx.x & 63;
    int wave = threadIdx.x >> 6;
    int g    = lane >> 3;                    // node within wave (0..7)
    int fp   = lane & 7;                     // uint4 index within row (feats 8fp..8fp+7)
    int node = blockIdx.x * 32 + wave * 8 + g;      // NN = 3125*32 exact
    int s = off[node], e = off[node + 1];
    int deg = e - s;
    float di = dinv[node];
    uint4 sw = Bm4[(size_t)node * 8 + fp];
    float a0 = u2lo(sw.x), a1 = u2hi(sw.x), a2 = u2lo(sw.y), a3 = u2hi(sw.y);
    float a4 = u2lo(sw.z), a5 = u2hi(sw.z), a6 = u2lo(sw.w), a7 = u2hi(sw.w);
    uint2 c0 = csr[s+0], c1 = csr[s+1], c2 = csr[s+2], c3 = csr[s+3];
    for (int j = 0; __any(j < deg); j += 4) {
        // prefetch next chunk (csr +128 pad keeps over-reads in-bounds)
        uint2 n0 = csr[s+j+4], n1 = csr[s+j+5], n2 = csr[s+j+6], n3 = csr[s+j+7];
        bool b0 = (j+0) < deg; u32 r0 = b0 ? c0.x : (u32)node; float w0 = b0 ? __uint_as_float(c0.y) : 0.f;
        bool b1 = (j+1) < deg; u32 r1 = b1 ? c1.x : (u32)node; float w1 = b1 ? __uint_as_float(c1.y) : 0.f;
        bool b2 = (j+2) < deg; u32 r2 = b2 ? c2.x : (u32)node; float w2 = b2 ? __uint_as_float(c2.y) : 0.f;
        bool b3 = (j+3) < deg; u32 r3 = b3 ? c3.x : (u32)node; float w3 = b3 ? __uint_as_float(c3.y) : 0.f;
        uint4 g0 = Bm4[(size_t)r0 * 8 + fp];
        uint4 g1 = Bm4[(size_t)r1 * 8 + fp];
        uint4 g2 = Bm4[(size_t)r2 * 8 + fp];
        uint4 g3 = Bm4[(size_t)r3 * 8 + fp];
        a0 += w0 * u2lo(g0.x) + w1 * u2lo(g1.x);
        a1 += w0 * u2hi(g0.x) + w1 * u2hi(g1.x);
        a2 += w0 * u2lo(g0.y) + w1 * u2lo(g1.y);
        a3 += w0 * u2hi(g0.y) + w1 * u2hi(g1.y);
        a4 += w0 * u2lo(g0.z) + w1 * u2lo(g1.z);
        a5 += w0 * u2hi(g0.z) + w1 * u2hi(g1.z);
        a6 += w0 * u2lo(g0.w) + w1 * u2lo(g1.w);
        a7 += w0 * u2hi(g0.w) + w1 * u2hi(g1.w);
        a0 += w2 * u2lo(g2.x) + w3 * u2lo(g3.x);
        a1 += w2 * u2hi(g2.x) + w3 * u2hi(g3.x);
        a2 += w2 * u2lo(g2.y) + w3 * u2lo(g3.y);
        a3 += w2 * u2hi(g2.y) + w3 * u2hi(g3.y);
        a4 += w2 * u2lo(g2.z) + w3 * u2lo(g3.z);
        a5 += w2 * u2hi(g2.z) + w3 * u2hi(g3.z);
        a6 += w2 * u2lo(g2.w) + w3 * u2lo(g3.w);
        a7 += w2 * u2hi(g2.w) + w3 * u2hi(g3.w);
        c0 = n0; c1 = n1; c2 = n2; c3 = n3;
    }
    float4 blo = *(const float4*)(bias + fp * 8);
    float4 bhi = *(const float4*)(bias + fp * 8 + 4);
    uint4 ov;
    ov.x = pk2(fmaxf(di * a0 + blo.x, 0.f), fmaxf(di * a1 + blo.y, 0.f));
    ov.y = pk2(fmaxf(di * a2 + blo.z, 0.f), fmaxf(di * a3 + blo.w, 0.f));
    ov.z = pk2(fmaxf(di * a4 + bhi.x, 0.f), fmaxf(di * a5 + bhi.y, 0.f));
    ov.w = pk2(fmaxf(di * a6 + bhi.z, 0.f), fmaxf(di * a7 + bhi.w, 0.f));
    outp[(size_t)node * 8 + fp] = ov;
}

// logits = H(bf16) @ Wo + bo ; out = log_softmax (MFMA, 3 col-tiles, zero-padded)
__launch_bounds__(256)
__global__ void k_out(const u16* __restrict__ Hm, const float* __restrict__ W,
                      const float* __restrict__ b, float* __restrict__ outp) {
    int lane = threadIdx.x & 63;
    int tile = blockIdx.x * 4 + (threadIdx.x >> 6);
    if (tile >= NTILE) return;
    int row = lane & 15;
    int kg  = lane >> 4;
    short8v bW[2][3];
    #pragma unroll
    for (int kt = 0; kt < 2; kt++)
        #pragma unroll
        for (int ct = 0; ct < 3; ct++) {
            int col = ct*16 + row;
            #pragma unroll
            for (int j = 0; j < 8; j++)
                bW[kt][ct][j] = (col < NC) ? (short)f2b(W[(kt*32 + kg*8 + j) * NC + col]) : (short)0;
        }
    int node0 = tile * 16;
    const u16* ar = Hm + (size_t)(node0 + row) * HD + kg * 8;
    short8v af0 = *(const short8v*)(ar);
    short8v af1 = *(const short8v*)(ar + 32);
    accf4 acc[3] = {};
    #pragma unroll
    for (int ct = 0; ct < 3; ct++) {
        acc[ct] = __builtin_amdgcn_mfma_f32_16x16x32_bf16(af0, bW[0][ct], acc[ct], 0, 0, 0);
        acc[ct] = __builtin_amdgcn_mfma_f32_16x16x32_bf16(af1, bW[1][ct], acc[ct], 0, 0, 0);
    }
    float bias0 = b[row];
    float bias1 = b[16 + row];
    bool  has2  = (32 + row) < NC;
    float bias2 = has2 ? b[32 + row] : 0.f;
    #pragma unroll
    for (int r = 0; r < 4; r++) {
        float l0 = acc[0][r] + bias0;
        float l1 = acc[1][r] + bias1;
        float l2 = has2 ? acc[2][r] + bias2 : -1e30f;
        float m = fmaxf(fmaxf(l0, l1), l2);
        #pragma unroll
        for (int s2 = 8; s2 > 0; s2 >>= 1) m = fmaxf(m, __shfl_xor(m, s2));
        float sum = expf(l0 - m) + expf(l1 - m) + (has2 ? expf(l2 - m) : 0.f);
        #pragma unroll
        for (int s2 = 8; s2 > 0; s2 >>= 1) sum += __shfl_xor(sum, s2);
        float ls = logf(sum);
        size_t base = (size_t)(node0 + kg*4 + r) * NC;
        outp[base + row]      = (l0 - m) - ls;
        outp[base + 16 + row] = (l1 - m) - ls;
        if (has2) outp[base + 32 + row] = (l2 - m) - ls;
    }
}

// ---------------- launch ----------------

extern "C" void kernel_launch(void* const* d_in, const int* in_sizes, int n_in,
                              void* d_out, int out_size, void* d_ws, size_t ws_size,
                              hipStream_t stream) {
    const float* x   = (const float*)d_in[0];
    const int*   ei  = (const int*)  d_in[1];
    const float* ew  = (const float*)d_in[2];
    const float* Wf  = (const float*)d_in[3];
    const float* bf  = (const float*)d_in[4];
    const float* Wc1 = (const float*)d_in[5];
    const float* bc1 = (const float*)d_in[6];
    const float* Wc2 = (const float*)d_in[7];
    const float* bc2 = (const float*)d_in[8];
    const float* Wo  = (const float*)d_in[9];
    const float* bo  = (const float*)d_in[10];
    float* out = (float*)d_out;

    char* w = (char*)d_ws;
    auto alloc = [&](size_t bytes) {
        char* p = w;
        w += (bytes + 511) & ~(size_t)511;
        return p;
    };
    u32*   hist = (u32*)  alloc((size_t)NBUK * NBLK * 4);
    u32*   btot = (u32*)  alloc((size_t)NBUK * 4);
    u32*   bst  = (u32*)  alloc((size_t)(NBUK + 1) * 4);
    float* dinv = (float*)alloc((size_t)NN * 4);
    int*   off  = (int*)  alloc((size_t)(NN + 1) * 4);
    uint2* rec  = (uint2*)alloc((size_t)NE * 8);
    uint2* csr  = (uint2*)alloc((size_t)(NE + 128) * 8);  // +128 pad for over-read
    u16*   hA   = (u16*)  alloc((size_t)NN * HD * 2);     // bf16 buffers
    u16*   hB   = (u16*)  alloc((size_t)NN * HD * 2);

    k_build1 <<<NBLK + MM_BLOCKS, 256, 0, stream>>>(ei, hist, x, Wf, bf, hA);
    k_bscan  <<<NBUK, 64, 0, stream>>>(hist, btot);
    k_bstart <<<1, 64, 0, stream>>>(btot, bst, off);
    k_scatter<<<NBLK, 256, 0, stream>>>(ei, ew, hist, bst, rec);
    k_bucket <<<NBUK, 256, 0, stream>>>(rec, bst, dinv, off, csr);

    k_mm64 <<<MM_BLOCKS, 256, 0, stream>>>(hA, Wc1, dinv, hB);
    k_agg  <<<NN / 32, 256, 0, stream>>>((const uint4*)hB, off, csr, dinv, bc1, (uint4*)hA);
    k_mm64 <<<MM_BLOCKS, 256, 0, stream>>>(hA, Wc2, dinv, hB);
    k_agg  <<<NN / 32, 256, 0, stream>>>((const uint4*)hB, off, csr, dinv, bc2, (uint4*)hA);
    k_out  <<<MM_BLOCKS, 256, 0, stream>>>(hA, Wo, bo, out);
}

// Round 14
// 168.656 us; speedup vs baseline: 1.1055x; 1.1055x over previous
//
#include <hip/hip_runtime.h>
#include <hip/hip_bf16.h>
#include <cstdint>
#include <cstddef>

#define NN 100000
#define NE 1600000
#define FIN 128
#define HD 64
#define NC 40
#define NTILE (NN / 16)                      // 6250 MFMA row-tiles
#define MM_BLOCKS ((NTILE + 3) / 4)          // 1563

#define BUK 256                              // nodes per bucket
#define NBUK ((NN + BUK - 1) / BUK)          // 391
#define EPB 1024                             // edges per hist/scatter block
#define NBLK ((NE + EPB - 1) / EPB)          // 1563

#define XSTR 68                              // build1 LDS row stride in u32
#define HSTR 36                              // agg-epilogue LDS row stride in u32 (72 bf16)

typedef unsigned short u16;
typedef unsigned int u32;
typedef __attribute__((ext_vector_type(8))) short short8v;
typedef __attribute__((ext_vector_type(4))) float accf4;

__device__ __forceinline__ float u2lo(u32 u) { return __uint_as_float(u << 16); }
__device__ __forceinline__ float u2hi(u32 u) { return __uint_as_float(u & 0xFFFF0000u); }
__device__ __forceinline__ u16 f2b(float f) {            // RNE f32->bf16
    u32 u = __float_as_uint(f);
    return (u16)((u + 0x7FFFu + ((u >> 16) & 1u)) >> 16);
}
__device__ __forceinline__ u32 pk2(float lo, float hi) {
    return (u32)f2b(lo) | ((u32)f2b(hi) << 16);
}

// ------- fused: per-block bucket histogram (LDS) || lin1 (LDS-staged x + MFMA) -------
__launch_bounds__(256)
__global__ void k_build1(const int* __restrict__ ei, u32* __restrict__ hist,
                         const float* __restrict__ x, const float* __restrict__ W,
                         const float* __restrict__ b, u16* __restrict__ out) {
    if (blockIdx.x < NBLK) {
        __shared__ u32 lh[NBUK];
        int blk = blockIdx.x, tid = threadIdx.x;
        for (int i = tid; i < NBUK; i += 256) lh[i] = 0;
        __syncthreads();
        #pragma unroll
        for (int it = 0; it < EPB / 256; it++) {
            int e = blk * EPB + it * 256 + tid;
            if (e < NE) {
                int col = ei[NE + e];
                atomicAdd(&lh[col >> 8], 1u);
            }
        }
        __syncthreads();
        for (int i = tid; i < NBUK; i += 256)
            hist[(size_t)blk * NBUK + i] = lh[i];      // transposed: coalesced write
        return;
    }
    // ---- lin1 half: stage 64 x-rows as bf16 in LDS (coalesced), then MFMA ----
    __shared__ u32 xs[64 * XSTR];
    int tid = threadIdx.x;
    int bi  = blockIdx.x - NBLK;
    int nodeB = bi * 64;
    const float4* x4 = (const float4*)x;
    for (int idx = tid; idx < 64 * 16; idx += 256) {
        int row = idx >> 4, seg = idx & 15;
        uint4 d = make_uint4(0u, 0u, 0u, 0u);
        if (nodeB + row < NN) {
            float4 a = x4[(size_t)(nodeB + row) * 32 + seg * 2];
            float4 c = x4[(size_t)(nodeB + row) * 32 + seg * 2 + 1];
            d.x = pk2(a.x, a.y);
            d.y = pk2(a.z, a.w);
            d.z = pk2(c.x, c.y);
            d.w = pk2(c.z, c.w);
        }
        *(uint4*)(xs + row * XSTR + seg * 4) = d;
    }
    __syncthreads();
    int lane = tid & 63;
    int wv   = tid >> 6;
    int tile = bi * 4 + wv;
    if (tile >= NTILE) return;
    int row = lane & 15;
    int kg  = lane >> 4;
    short8v bW[4][4];
    #pragma unroll
    for (int kt = 0; kt < 4; kt++)
        #pragma unroll
        for (int ct = 0; ct < 4; ct++)
            #pragma unroll
            for (int j = 0; j < 8; j++)
                bW[kt][ct][j] = (short)f2b(W[(kt*32 + kg*8 + j) * HD + ct*16 + row]);
    int node0 = tile * 16;
    short8v af[4];
    #pragma unroll
    for (int kt = 0; kt < 4; kt++)
        af[kt] = *(const short8v*)(xs + (wv*16 + row) * XSTR + kt * 16 + kg * 4);
    accf4 acc[4] = {};
    #pragma unroll
    for (int kt = 0; kt < 4; kt++)
        #pragma unroll
        for (int ct = 0; ct < 4; ct++)
            acc[ct] = __builtin_amdgcn_mfma_f32_16x16x32_bf16(af[kt], bW[kt][ct], acc[ct], 0, 0, 0);
    #pragma unroll
    for (int ct = 0; ct < 4; ct++) {
        float bias = b[ct*16 + row];
        #pragma unroll
        for (int r = 0; r < 4; r++) {
            float v = fmaxf(acc[ct][r] + bias, 0.f);
            out[(size_t)(node0 + kg*4 + r) * HD + ct*16 + row] = f2b(v);
        }
    }
}

// per-bucket exclusive prefix over blocks (in place, transposed layout); total -> bucketTotal
__global__ void k_bscan(u32* __restrict__ hist, u32* __restrict__ bucketTotal) {
    int b = blockIdx.x;
    int lane = threadIdx.x;                  // 64 threads
    u32 carry = 0;
    for (int j0 = 0; j0 < NBLK; j0 += 64) {
        int j = j0 + lane;
        u32 v = (j < NBLK) ? hist[(size_t)j * NBUK + b] : 0;
        u32 inc = v;
        #pragma unroll
        for (int d = 1; d < 64; d <<= 1) {
            u32 t = __shfl_up(inc, d);
            if (lane >= d) inc += t;
        }
        if (j < NBLK) hist[(size_t)j * NBUK + b] = carry + inc - v;
        carry += __shfl(inc, 63);
    }
    if (lane == 0) bucketTotal[b] = carry;
}

// scan bucketTotal -> bucketStart (exclusive); bucketStart[NBUK]=NE; off[NN]=NE
__global__ void k_bstart(const u32* __restrict__ bucketTotal, u32* __restrict__ bucketStart,
                         int* __restrict__ off) {
    int lane = threadIdx.x;                  // 64 threads
    u32 carry = 0;
    for (int j0 = 0; j0 < NBUK; j0 += 64) {
        int j = j0 + lane;
        u32 v = (j < NBUK) ? bucketTotal[j] : 0;
        u32 inc = v;
        #pragma unroll
        for (int d = 1; d < 64; d <<= 1) {
            u32 t = __shfl_up(inc, d);
            if (lane >= d) inc += t;
        }
        if (j < NBUK) bucketStart[j] = carry + inc - v;
        carry += __shfl(inc, 63);
    }
    if (lane == 0) { bucketStart[NBUK] = carry; off[NN] = (int)carry; }
}

// scatter edges into bucket segments: rank via LDS atomics; one packed 8B record
// rec.x = row | (in-bucket col << 24), rec.y = raw ew bits
__launch_bounds__(256)
__global__ void k_scatter(const int* __restrict__ ei, const float* __restrict__ ew,
                          const u32* __restrict__ hist, const u32* __restrict__ bucketStart,
                          uint2* __restrict__ rec) {
    __shared__ u32 lh[NBUK];
    __shared__ u32 gb[NBUK];
    int blk = blockIdx.x, tid = threadIdx.x;
    for (int i = tid; i < NBUK; i += 256) {
        lh[i] = 0;
        gb[i] = bucketStart[i] + hist[(size_t)blk * NBUK + i];   // coalesced
    }
    __syncthreads();
    #pragma unroll
    for (int it = 0; it < EPB / 256; it++) {
        int e = blk * EPB + it * 256 + tid;
        if (e < NE) {
            int row = ei[e], col = ei[NE + e];
            float wv = ew[e];
            int bkt = col >> 8;
            u32 cl = (u32)(col & 255);
            u32 r = atomicAdd(&lh[bkt], 1u);
            u32 slot = gb[bkt] + r;
            rec[slot] = make_uint2((u32)row | (cl << 24), __float_as_uint(wv));
        }
    }
}

// per-bucket CSR build: packed LDS hist -> dinv, off, csr=(row, raw ew)
__launch_bounds__(256)
__global__ void k_bucket(const uint2* __restrict__ rec, const u32* __restrict__ bucketStart,
                         float* __restrict__ dinv, int* __restrict__ off,
                         uint2* __restrict__ csr) {
    __shared__ u32 lpk[BUK];
    __shared__ u32 loff[BUK];
    __shared__ u32 wt[4];
    int b = blockIdx.x, tid = threadIdx.x;
    int base = b * BUK;
    u32 seg0 = bucketStart[b], seg1 = bucketStart[b + 1];
    int nb = (int)(seg1 - seg0);
    lpk[tid] = 0;
    __syncthreads();
    for (int idx = tid; idx < nb; idx += 256) {
        uint2 ab = rec[seg0 + idx];
        u32 cl = ab.x >> 24;
        u32 fx = __float2uint_rn(__uint_as_float(ab.y) * 16384.0f);   // Q6.14
        atomicAdd(&lpk[cl], (1u << 20) | fx);
    }
    __syncthreads();
    u32 pk = lpk[tid];
    u32 cnt = pk >> 20;
    int node = base + tid;
    if (node < NN) dinv[node] = rsqrtf(1.0f + (float)(pk & 0xFFFFFu) * (1.0f / 16384.0f));
    int lane = tid & 63, wid = tid >> 6;
    u32 inc = cnt;
    #pragma unroll
    for (int d = 1; d < 64; d <<= 1) {
        u32 t = __shfl_up(inc, d);
        if (lane >= d) inc += t;
    }
    if (lane == 63) wt[wid] = inc;
    __syncthreads();
    u32 wof = 0;
    #pragma unroll
    for (int k = 0; k < 4; k++) if (k < wid) wof += wt[k];
    loff[tid] = wof + inc - cnt;
    if (node < NN) off[node] = (int)(seg0 + loff[tid]);
    lpk[tid] = 0;                    // reuse as rank counters
    __syncthreads();
    for (int idx = tid; idx < nb; idx += 256) {
        uint2 ab = rec[seg0 + idx];
        u32 cl = ab.x >> 24;
        u32 r2 = atomicAdd(&lpk[cl], 1u);
        csr[seg0 + loff[cl] + r2] = make_uint2(ab.x & 0xFFFFFFu, ab.y);   // (row, raw ew)
    }
}

// out(bf16) = dinv-scaled A(bf16) @ W: tbl'[r] = dinv[r] * (A@W)[r]   (conv1 table)
__launch_bounds__(256)
__global__ void k_mm64(const u16* __restrict__ A, const float* __restrict__ W,
                       const float* __restrict__ dinv, u16* __restrict__ out) {
    int lane = threadIdx.x & 63;
    int tile = blockIdx.x * 4 + (threadIdx.x >> 6);
    if (tile >= NTILE) return;
    int row = lane & 15;
    int kg  = lane >> 4;
    short8v bW[2][4];
    #pragma unroll
    for (int kt = 0; kt < 2; kt++)
        #pragma unroll
        for (int ct = 0; ct < 4; ct++)
            #pragma unroll
            for (int j = 0; j < 8; j++)
                bW[kt][ct][j] = (short)f2b(W[(kt*32 + kg*8 + j) * HD + ct*16 + row]);
    int node0 = tile * 16;
    const u16* ar = A + (size_t)(node0 + row) * HD + kg * 8;
    short8v af0 = *(const short8v*)(ar);
    short8v af1 = *(const short8v*)(ar + 32);
    accf4 acc[4] = {};
    #pragma unroll
    for (int ct = 0; ct < 4; ct++) {
        acc[ct] = __builtin_amdgcn_mfma_f32_16x16x32_bf16(af0, bW[0][ct], acc[ct], 0, 0, 0);
        acc[ct] = __builtin_amdgcn_mfma_f32_16x16x32_bf16(af1, bW[1][ct], acc[ct], 0, 0, 0);
    }
    float dr[4];
    #pragma unroll
    for (int r = 0; r < 4; r++) dr[r] = dinv[node0 + kg*4 + r];
    #pragma unroll
    for (int ct = 0; ct < 4; ct++)
        #pragma unroll
        for (int r = 0; r < 4; r++)
            out[(size_t)(node0 + kg*4 + r) * HD + ct*16 + row] = f2b(acc[ct][r] * dr[r]);
}

// ---- fused agg(conv1) + mm64(conv2): gather -> h1 (LDS) -> MFMA -> tbl2 ----
__launch_bounds__(256)
__global__ void k_aggmm(const uint4* __restrict__ Bm4, const int* __restrict__ off,
                        const uint2* __restrict__ csr, const float* __restrict__ dinv,
                        const float* __restrict__ bias, const float* __restrict__ W2,
                        u16* __restrict__ tbl2) {
    __shared__ u32 hs[32 * HSTR];            // 32 h1-rows, stride 72 bf16
    int lane = threadIdx.x & 63;
    int wave = threadIdx.x >> 6;
    int g    = lane >> 3;
    int fp   = lane & 7;
    int node = blockIdx.x * 32 + wave * 8 + g;
    int s = off[node], e = off[node + 1];
    int deg = e - s;
    float di = dinv[node];
    uint4 sw = Bm4[(size_t)node * 8 + fp];
    float a0 = u2lo(sw.x), a1 = u2hi(sw.x), a2 = u2lo(sw.y), a3 = u2hi(sw.y);
    float a4 = u2lo(sw.z), a5 = u2hi(sw.z), a6 = u2lo(sw.w), a7 = u2hi(sw.w);
    uint2 c0 = csr[s+0], c1 = csr[s+1], c2 = csr[s+2], c3 = csr[s+3];
    for (int j = 0; __any(j < deg); j += 4) {
        uint2 n0 = csr[s+j+4], n1 = csr[s+j+5], n2 = csr[s+j+6], n3 = csr[s+j+7];
        bool b0 = (j+0) < deg; u32 r0 = b0 ? c0.x : (u32)node; float w0 = b0 ? __uint_as_float(c0.y) : 0.f;
        bool b1 = (j+1) < deg; u32 r1 = b1 ? c1.x : (u32)node; float w1 = b1 ? __uint_as_float(c1.y) : 0.f;
        bool b2 = (j+2) < deg; u32 r2 = b2 ? c2.x : (u32)node; float w2 = b2 ? __uint_as_float(c2.y) : 0.f;
        bool b3 = (j+3) < deg; u32 r3 = b3 ? c3.x : (u32)node; float w3 = b3 ? __uint_as_float(c3.y) : 0.f;
        uint4 g0 = Bm4[(size_t)r0 * 8 + fp];
        uint4 g1 = Bm4[(size_t)r1 * 8 + fp];
        uint4 g2 = Bm4[(size_t)r2 * 8 + fp];
        uint4 g3 = Bm4[(size_t)r3 * 8 + fp];
        a0 += w0*u2lo(g0.x) + w1*u2lo(g1.x) + w2*u2lo(g2.x) + w3*u2lo(g3.x);
        a1 += w0*u2hi(g0.x) + w1*u2hi(g1.x) + w2*u2hi(g2.x) + w3*u2hi(g3.x);
        a2 += w0*u2lo(g0.y) + w1*u2lo(g1.y) + w2*u2lo(g2.y) + w3*u2lo(g3.y);
        a3 += w0*u2hi(g0.y) + w1*u2hi(g1.y) + w2*u2hi(g2.y) + w3*u2hi(g3.y);
        a4 += w0*u2lo(g0.z) + w1*u2lo(g1.z) + w2*u2lo(g2.z) + w3*u2lo(g3.z);
        a5 += w0*u2hi(g0.z) + w1*u2hi(g1.z) + w2*u2hi(g2.z) + w3*u2hi(g3.z);
        a6 += w0*u2lo(g0.w) + w1*u2lo(g1.w) + w2*u2lo(g2.w) + w3*u2lo(g3.w);
        a7 += w0*u2hi(g0.w) + w1*u2hi(g1.w) + w2*u2hi(g2.w) + w3*u2hi(g3.w);
        c0 = n0; c1 = n1; c2 = n2; c3 = n3;
    }
    float4 blo = *(const float4*)(bias + fp * 8);
    float4 bhi = *(const float4*)(bias + fp * 8 + 4);
    int lrow = wave * 8 + g;
    uint4 hv;
    hv.x = pk2(fmaxf(di*a0 + blo.x, 0.f), fmaxf(di*a1 + blo.y, 0.f));
    hv.y = pk2(fmaxf(di*a2 + blo.z, 0.f), fmaxf(di*a3 + blo.w, 0.f));
    hv.z = pk2(fmaxf(di*a4 + bhi.x, 0.f), fmaxf(di*a5 + bhi.y, 0.f));
    hv.w = pk2(fmaxf(di*a6 + bhi.z, 0.f), fmaxf(di*a7 + bhi.w, 0.f));
    *(uint4*)(hs + lrow * HSTR + fp * 4) = hv;
    __syncthreads();
    // mm64 phase: wave w -> tile t=w&1 (16 rows), col-tiles ctbase..ctbase+1
    int row = lane & 15;
    int kg  = lane >> 4;
    int t      = wave & 1;
    int ctbase = (wave >> 1) * 2;
    short8v bW[2][2];
    #pragma unroll
    for (int kt = 0; kt < 2; kt++)
        #pragma unroll
        for (int cc = 0; cc < 2; cc++)
            #pragma unroll
            for (int j = 0; j < 8; j++)
                bW[kt][cc][j] = (short)f2b(W2[(kt*32 + kg*8 + j) * HD + (ctbase+cc)*16 + row]);
    short8v af0 = *(const short8v*)(hs + (t*16 + row) * HSTR + kg * 4);
    short8v af1 = *(const short8v*)(hs + (t*16 + row) * HSTR + 16 + kg * 4);
    accf4 acc[2] = {};
    #pragma unroll
    for (int cc = 0; cc < 2; cc++) {
        acc[cc] = __builtin_amdgcn_mfma_f32_16x16x32_bf16(af0, bW[0][cc], acc[cc], 0, 0, 0);
        acc[cc] = __builtin_amdgcn_mfma_f32_16x16x32_bf16(af1, bW[1][cc], acc[cc], 0, 0, 0);
    }
    int node0 = blockIdx.x * 32 + t * 16;
    float dr[4];
    #pragma unroll
    for (int r = 0; r < 4; r++) dr[r] = dinv[node0 + kg*4 + r];
    #pragma unroll
    for (int cc = 0; cc < 2; cc++)
        #pragma unroll
        for (int r = 0; r < 4; r++)
            tbl2[(size_t)(node0 + kg*4 + r) * HD + (ctbase+cc)*16 + row] = f2b(acc[cc][r] * dr[r]);
}

// ---- fused agg(conv2) + lin2 + log_softmax ----
__launch_bounds__(256)
__global__ void k_aggout(const uint4* __restrict__ Bm4, const int* __restrict__ off,
                         const uint2* __restrict__ csr, const float* __restrict__ dinv,
                         const float* __restrict__ bias, const float* __restrict__ Wo,
                         const float* __restrict__ bo, float* __restrict__ outp) {
    __shared__ u32 hs[32 * HSTR];
    int lane = threadIdx.x & 63;
    int wave = threadIdx.x >> 6;
    int g    = lane >> 3;
    int fp   = lane & 7;
    int node = blockIdx.x * 32 + wave * 8 + g;
    int s = off[node], e = off[node + 1];
    int deg = e - s;
    float di = dinv[node];
    uint4 sw = Bm4[(size_t)node * 8 + fp];
    float a0 = u2lo(sw.x), a1 = u2hi(sw.x), a2 = u2lo(sw.y), a3 = u2hi(sw.y);
    float a4 = u2lo(sw.z), a5 = u2hi(sw.z), a6 = u2lo(sw.w), a7 = u2hi(sw.w);
    uint2 c0 = csr[s+0], c1 = csr[s+1], c2 = csr[s+2], c3 = csr[s+3];
    for (int j = 0; __any(j < deg); j += 4) {
        uint2 n0 = csr[s+j+4], n1 = csr[s+j+5], n2 = csr[s+j+6], n3 = csr[s+j+7];
        bool b0 = (j+0) < deg; u32 r0 = b0 ? c0.x : (u32)node; float w0 = b0 ? __uint_as_float(c0.y) : 0.f;
        bool b1 = (j+1) < deg; u32 r1 = b1 ? c1.x : (u32)node; float w1 = b1 ? __uint_as_float(c1.y) : 0.f;
        bool b2 = (j+2) < deg; u32 r2 = b2 ? c2.x : (u32)node; float w2 = b2 ? __uint_as_float(c2.y) : 0.f;
        bool b3 = (j+3) < deg; u32 r3 = b3 ? c3.x : (u32)node; float w3 = b3 ? __uint_as_float(c3.y) : 0.f;
        uint4 g0 = Bm4[(size_t)r0 * 8 + fp];
        uint4 g1 = Bm4[(size_t)r1 * 8 + fp];
        uint4 g2 = Bm4[(size_t)r2 * 8 + fp];
        uint4 g3 = Bm4[(size_t)r3 * 8 + fp];
        a0 += w0*u2lo(g0.x) + w1*u2lo(g1.x) + w2*u2lo(g2.x) + w3*u2lo(g3.x);
        a1 += w0*u2hi(g0.x) + w1*u2hi(g1.x) + w2*u2hi(g2.x) + w3*u2hi(g3.x);
        a2 += w0*u2lo(g0.y) + w1*u2lo(g1.y) + w2*u2lo(g2.y) + w3*u2lo(g3.y);
        a3 += w0*u2hi(g0.y) + w1*u2hi(g1.y) + w2*u2hi(g2.y) + w3*u2hi(g3.y);
        a4 += w0*u2lo(g0.z) + w1*u2lo(g1.z) + w2*u2lo(g2.z) + w3*u2lo(g3.z);
        a5 += w0*u2hi(g0.z) + w1*u2hi(g1.z) + w2*u2hi(g2.z) + w3*u2hi(g3.z);
        a6 += w0*u2lo(g0.w) + w1*u2lo(g1.w) + w2*u2lo(g2.w) + w3*u2lo(g3.w);
        a7 += w0*u2hi(g0.w) + w1*u2hi(g1.w) + w2*u2hi(g2.w) + w3*u2hi(g3.w);
        c0 = n0; c1 = n1; c2 = n2; c3 = n3;
    }
    float4 blo = *(const float4*)(bias + fp * 8);
    float4 bhi = *(const float4*)(bias + fp * 8 + 4);
    int lrow = wave * 8 + g;
    uint4 hv;
    hv.x = pk2(fmaxf(di*a0 + blo.x, 0.f), fmaxf(di*a1 + blo.y, 0.f));
    hv.y = pk2(fmaxf(di*a2 + blo.z, 0.f), fmaxf(di*a3 + blo.w, 0.f));
    hv.z = pk2(fmaxf(di*a4 + bhi.x, 0.f), fmaxf(di*a5 + bhi.y, 0.f));
    hv.w = pk2(fmaxf(di*a6 + bhi.z, 0.f), fmaxf(di*a7 + bhi.w, 0.f));
    *(uint4*)(hs + lrow * HSTR + fp * 4) = hv;
    __syncthreads();
    if (wave >= 2) return;                   // waves 0,1 each do one 16-row tile
    int row = lane & 15;
    int kg  = lane >> 4;
    int t = wave;
    short8v bW[2][3];
    #pragma unroll
    for (int kt = 0; kt < 2; kt++)
        #pragma unroll
        for (int ct = 0; ct < 3; ct++) {
            int col = ct*16 + row;
            #pragma unroll
            for (int j = 0; j < 8; j++)
                bW[kt][ct][j] = (col < NC) ? (short)f2b(Wo[(kt*32 + kg*8 + j) * NC + col]) : (short)0;
        }
    short8v af0 = *(const short8v*)(hs + (t*16 + row) * HSTR + kg * 4);
    short8v af1 = *(const short8v*)(hs + (t*16 + row) * HSTR + 16 + kg * 4);
    accf4 acc[3] = {};
    #pragma unroll
    for (int ct = 0; ct < 3; ct++) {
        acc[ct] = __builtin_amdgcn_mfma_f32_16x16x32_bf16(af0, bW[0][ct], acc[ct], 0, 0, 0);
        acc[ct] = __builtin_amdgcn_mfma_f32_16x16x32_bf16(af1, bW[1][ct], acc[ct], 0, 0, 0);
    }
    int node0 = blockIdx.x * 32 + t * 16;
    float bias0 = bo[row];
    float bias1 = bo[16 + row];
    bool  has2  = (32 + row) < NC;
    float bias2 = has2 ? bo[32 + row] : 0.f;
    #pragma unroll
    for (int r = 0; r < 4; r++) {
        float l0 = acc[0][r] + bias0;
        float l1 = acc[1][r] + bias1;
        float l2 = has2 ? acc[2][r] + bias2 : -1e30f;
        float m = fmaxf(fmaxf(l0, l1), l2);
        #pragma unroll
        for (int s2 = 8; s2 > 0; s2 >>= 1) m = fmaxf(m, __shfl_xor(m, s2));
        float sum = expf(l0 - m) + expf(l1 - m) + (has2 ? expf(l2 - m) : 0.f);
        #pragma unroll
        for (int s2 = 8; s2 > 0; s2 >>= 1) sum += __shfl_xor(sum, s2);
        float ls = logf(sum);
        size_t base = (size_t)(node0 + kg*4 + r) * NC;
        outp[base + row]      = (l0 - m) - ls;
        outp[base + 16 + row] = (l1 - m) - ls;
        if (has2) outp[base + 32 + row] = (l2 - m) - ls;
    }
}

// ---------------- launch ----------------

extern "C" void kernel_launch(void* const* d_in, const int* in_sizes, int n_in,
                              void* d_out, int out_size, void* d_ws, size_t ws_size,
                              hipStream_t stream) {
    const float* x   = (const float*)d_in[0];
    const int*   ei  = (const int*)  d_in[1];
    const float* ew  = (const float*)d_in[2];
    const float* Wf  = (const float*)d_in[3];
    const float* bf  = (const float*)d_in[4];
    const float* Wc1 = (const float*)d_in[5];
    const float* bc1 = (const float*)d_in[6];
    const float* Wc2 = (const float*)d_in[7];
    const float* bc2 = (const float*)d_in[8];
    const float* Wo  = (const float*)d_in[9];
    const float* bo  = (const float*)d_in[10];
    float* out = (float*)d_out;

    char* w = (char*)d_ws;
    auto alloc = [&](size_t bytes) {
        char* p = w;
        w += (bytes + 511) & ~(size_t)511;
        return p;
    };
    u32*   hist = (u32*)  alloc((size_t)NBLK * NBUK * 4);
    u32*   btot = (u32*)  alloc((size_t)NBUK * 4);
    u32*   bst  = (u32*)  alloc((size_t)(NBUK + 1) * 4);
    float* dinv = (float*)alloc((size_t)NN * 4);
    int*   off  = (int*)  alloc((size_t)(NN + 1) * 4);
    uint2* rec  = (uint2*)alloc((size_t)NE * 8);
    uint2* csr  = (uint2*)alloc((size_t)(NE + 128) * 8);  // +128 pad for over-read
    u16*   hA   = (u16*)  alloc((size_t)NN * HD * 2);     // bf16 buffers
    u16*   hB   = (u16*)  alloc((size_t)NN * HD * 2);

    k_build1 <<<NBLK + MM_BLOCKS, 256, 0, stream>>>(ei, hist, x, Wf, bf, hA);
    k_bscan  <<<NBUK, 64, 0, stream>>>(hist, btot);
    k_bstart <<<1, 64, 0, stream>>>(btot, bst, off);
    k_scatter<<<NBLK, 256, 0, stream>>>(ei, ew, hist, bst, rec);
    k_bucket <<<NBUK, 256, 0, stream>>>(rec, bst, dinv, off, csr);

    k_mm64  <<<MM_BLOCKS, 256, 0, stream>>>(hA, Wc1, dinv, hB);                 // tbl1
    k_aggmm <<<NN / 32, 256, 0, stream>>>((const uint4*)hB, off, csr, dinv, bc1, Wc2, hA);  // tbl2
    k_aggout<<<NN / 32, 256, 0, stream>>>((const uint4*)hA, off, csr, dinv, bc2, Wo, bo, out);
}

// Round 15
// 163.302 us; speedup vs baseline: 1.1418x; 1.0328x over previous
//
#include <hip/hip_runtime.h>
#include <hip/hip_bf16.h>
#include <cstdint>
#include <cstddef>

#define NN 100000
#define NE 1600000
#define FIN 128
#define HD 64
#define NC 40
#define NTILE (NN / 16)                      // 6250 MFMA row-tiles
#define MM_BLOCKS ((NTILE + 3) / 4)          // 1563

#define BUK 256                              // nodes per bucket
#define NBUK ((NN + BUK - 1) / BUK)          // 391
#define EPB 1024                             // edges per hist/scatter block
#define NBLK ((NE + EPB - 1) / EPB)          // 1563

#define XSTR 68                              // build1 LDS row stride in u32
#define HSTR 36                              // agg-epilogue LDS row stride in u32 (72 bf16)

typedef unsigned short u16;
typedef unsigned int u32;
typedef __attribute__((ext_vector_type(8))) short short8v;
typedef __attribute__((ext_vector_type(4))) float accf4;
typedef __attribute__((ext_vector_type(2))) float f32x2;

__device__ __forceinline__ float u2lo(u32 u) { return __uint_as_float(u << 16); }
__device__ __forceinline__ float u2hi(u32 u) { return __uint_as_float(u & 0xFFFF0000u); }
__device__ __forceinline__ u16 f2b(float f) {            // RNE f32->bf16
    u32 u = __float_as_uint(f);
    return (u16)((u + 0x7FFFu + ((u >> 16) & 1u)) >> 16);
}
__device__ __forceinline__ u32 pk2(float lo, float hi) {
    return (u32)f2b(lo) | ((u32)f2b(hi) << 16);
}
__device__ __forceinline__ unsigned char f2fp8(float v) {   // f32 -> fp8 e4m3 (OCP)
    int r = __builtin_amdgcn_cvt_pk_fp8_f32(v, 0.f, 0, false);
    return (unsigned char)(r & 0xFF);
}

// ------- fused: per-block bucket histogram (LDS) || lin1 (LDS-staged x + MFMA) -------
__launch_bounds__(256)
__global__ void k_build1(const int* __restrict__ ei, u32* __restrict__ hist,
                         const float* __restrict__ x, const float* __restrict__ W,
                         const float* __restrict__ b, u16* __restrict__ out) {
    if (blockIdx.x < NBLK) {
        __shared__ u32 lh[NBUK];
        int blk = blockIdx.x, tid = threadIdx.x;
        for (int i = tid; i < NBUK; i += 256) lh[i] = 0;
        __syncthreads();
        #pragma unroll
        for (int it = 0; it < EPB / 256; it++) {
            int e = blk * EPB + it * 256 + tid;
            if (e < NE) {
                int col = ei[NE + e];
                atomicAdd(&lh[col >> 8], 1u);
            }
        }
        __syncthreads();
        for (int i = tid; i < NBUK; i += 256)
            hist[(size_t)blk * NBUK + i] = lh[i];      // transposed: coalesced write
        return;
    }
    // ---- lin1 half: stage 64 x-rows as bf16 in LDS (coalesced), then MFMA ----
    __shared__ u32 xs[64 * XSTR];
    int tid = threadIdx.x;
    int bi  = blockIdx.x - NBLK;
    int nodeB = bi * 64;
    const float4* x4 = (const float4*)x;
    for (int idx = tid; idx < 64 * 16; idx += 256) {
        int row = idx >> 4, seg = idx & 15;
        uint4 d = make_uint4(0u, 0u, 0u, 0u);
        if (nodeB + row < NN) {
            float4 a = x4[(size_t)(nodeB + row) * 32 + seg * 2];
            float4 c = x4[(size_t)(nodeB + row) * 32 + seg * 2 + 1];
            d.x = pk2(a.x, a.y);
            d.y = pk2(a.z, a.w);
            d.z = pk2(c.x, c.y);
            d.w = pk2(c.z, c.w);
        }
        *(uint4*)(xs + row * XSTR + seg * 4) = d;
    }
    __syncthreads();
    int lane = tid & 63;
    int wv   = tid >> 6;
    int tile = bi * 4 + wv;
    if (tile >= NTILE) return;
    int row = lane & 15;
    int kg  = lane >> 4;
    short8v bW[4][4];
    #pragma unroll
    for (int kt = 0; kt < 4; kt++)
        #pragma unroll
        for (int ct = 0; ct < 4; ct++)
            #pragma unroll
            for (int j = 0; j < 8; j++)
                bW[kt][ct][j] = (short)f2b(W[(kt*32 + kg*8 + j) * HD + ct*16 + row]);
    int node0 = tile * 16;
    short8v af[4];
    #pragma unroll
    for (int kt = 0; kt < 4; kt++)
        af[kt] = *(const short8v*)(xs + (wv*16 + row) * XSTR + kt * 16 + kg * 4);
    accf4 acc[4] = {};
    #pragma unroll
    for (int kt = 0; kt < 4; kt++)
        #pragma unroll
        for (int ct = 0; ct < 4; ct++)
            acc[ct] = __builtin_amdgcn_mfma_f32_16x16x32_bf16(af[kt], bW[kt][ct], acc[ct], 0, 0, 0);
    #pragma unroll
    for (int ct = 0; ct < 4; ct++) {
        float bias = b[ct*16 + row];
        #pragma unroll
        for (int r = 0; r < 4; r++) {
            float v = fmaxf(acc[ct][r] + bias, 0.f);
            out[(size_t)(node0 + kg*4 + r) * HD + ct*16 + row] = f2b(v);
        }
    }
}

// per-bucket exclusive prefix over blocks (in place, transposed layout); total -> bucketTotal
__global__ void k_bscan(u32* __restrict__ hist, u32* __restrict__ bucketTotal) {
    int b = blockIdx.x;
    int lane = threadIdx.x;                  // 64 threads
    u32 carry = 0;
    for (int j0 = 0; j0 < NBLK; j0 += 64) {
        int j = j0 + lane;
        u32 v = (j < NBLK) ? hist[(size_t)j * NBUK + b] : 0;
        u32 inc = v;
        #pragma unroll
        for (int d = 1; d < 64; d <<= 1) {
            u32 t = __shfl_up(inc, d);
            if (lane >= d) inc += t;
        }
        if (j < NBLK) hist[(size_t)j * NBUK + b] = carry + inc - v;
        carry += __shfl(inc, 63);
    }
    if (lane == 0) bucketTotal[b] = carry;
}

// scan bucketTotal -> bucketStart (exclusive); bucketStart[NBUK]=NE; off[NN]=NE
__global__ void k_bstart(const u32* __restrict__ bucketTotal, u32* __restrict__ bucketStart,
                         int* __restrict__ off) {
    int lane = threadIdx.x;                  // 64 threads
    u32 carry = 0;
    for (int j0 = 0; j0 < NBUK; j0 += 64) {
        int j = j0 + lane;
        u32 v = (j < NBUK) ? bucketTotal[j] : 0;
        u32 inc = v;
        #pragma unroll
        for (int d = 1; d < 64; d <<= 1) {
            u32 t = __shfl_up(inc, d);
            if (lane >= d) inc += t;
        }
        if (j < NBUK) bucketStart[j] = carry + inc - v;
        carry += __shfl(inc, 63);
    }
    if (lane == 0) { bucketStart[NBUK] = carry; off[NN] = (int)carry; }
}

// scatter edges into bucket segments: rank via LDS atomics; one packed 8B record
// rec.x = row | (in-bucket col << 24), rec.y = raw ew bits
__launch_bounds__(256)
__global__ void k_scatter(const int* __restrict__ ei, const float* __restrict__ ew,
                          const u32* __restrict__ hist, const u32* __restrict__ bucketStart,
                          uint2* __restrict__ rec) {
    __shared__ u32 lh[NBUK];
    __shared__ u32 gb[NBUK];
    int blk = blockIdx.x, tid = threadIdx.x;
    for (int i = tid; i < NBUK; i += 256) {
        lh[i] = 0;
        gb[i] = bucketStart[i] + hist[(size_t)blk * NBUK + i];   // coalesced
    }
    __syncthreads();
    #pragma unroll
    for (int it = 0; it < EPB / 256; it++) {
        int e = blk * EPB + it * 256 + tid;
        if (e < NE) {
            int row = ei[e], col = ei[NE + e];
            float wv = ew[e];
            int bkt = col >> 8;
            u32 cl = (u32)(col & 255);
            u32 r = atomicAdd(&lh[bkt], 1u);
            u32 slot = gb[bkt] + r;
            rec[slot] = make_uint2((u32)row | (cl << 24), __float_as_uint(wv));
        }
    }
}

// per-bucket CSR build: packed LDS hist -> dinv, off, csr=(row, raw ew)
__launch_bounds__(256)
__global__ void k_bucket(const uint2* __restrict__ rec, const u32* __restrict__ bucketStart,
                         float* __restrict__ dinv, int* __restrict__ off,
                         uint2* __restrict__ csr) {
    __shared__ u32 lpk[BUK];
    __shared__ u32 loff[BUK];
    __shared__ u32 wt[4];
    int b = blockIdx.x, tid = threadIdx.x;
    int base = b * BUK;
    u32 seg0 = bucketStart[b], seg1 = bucketStart[b + 1];
    int nb = (int)(seg1 - seg0);
    lpk[tid] = 0;
    __syncthreads();
    for (int idx = tid; idx < nb; idx += 256) {
        uint2 ab = rec[seg0 + idx];
        u32 cl = ab.x >> 24;
        u32 fx = __float2uint_rn(__uint_as_float(ab.y) * 16384.0f);   // Q6.14
        atomicAdd(&lpk[cl], (1u << 20) | fx);
    }
    __syncthreads();
    u32 pk = lpk[tid];
    u32 cnt = pk >> 20;
    int node = base + tid;
    if (node < NN) dinv[node] = rsqrtf(1.0f + (float)(pk & 0xFFFFFu) * (1.0f / 16384.0f));
    int lane = tid & 63, wid = tid >> 6;
    u32 inc = cnt;
    #pragma unroll
    for (int d = 1; d < 64; d <<= 1) {
        u32 t = __shfl_up(inc, d);
        if (lane >= d) inc += t;
    }
    if (lane == 63) wt[wid] = inc;
    __syncthreads();
    u32 wof = 0;
    #pragma unroll
    for (int k = 0; k < 4; k++) if (k < wid) wof += wt[k];
    loff[tid] = wof + inc - cnt;
    if (node < NN) off[node] = (int)(seg0 + loff[tid]);
    lpk[tid] = 0;                    // reuse as rank counters
    __syncthreads();
    for (int idx = tid; idx < nb; idx += 256) {
        uint2 ab = rec[seg0 + idx];
        u32 cl = ab.x >> 24;
        u32 r2 = atomicAdd(&lpk[cl], 1u);
        csr[seg0 + loff[cl] + r2] = make_uint2(ab.x & 0xFFFFFFu, ab.y);   // (row, raw ew)
    }
}

// out(bf16) = dinv-scaled A(bf16) @ W: tbl'[r] = dinv[r] * (A@W)[r]   (conv1 table, bf16)
__launch_bounds__(256)
__global__ void k_mm64(const u16* __restrict__ A, const float* __restrict__ W,
                       const float* __restrict__ dinv, u16* __restrict__ out) {
    int lane = threadIdx.x & 63;
    int tile = blockIdx.x * 4 + (threadIdx.x >> 6);
    if (tile >= NTILE) return;
    int row = lane & 15;
    int kg  = lane >> 4;
    short8v bW[2][4];
    #pragma unroll
    for (int kt = 0; kt < 2; kt++)
        #pragma unroll
        for (int ct = 0; ct < 4; ct++)
            #pragma unroll
            for (int j = 0; j < 8; j++)
                bW[kt][ct][j] = (short)f2b(W[(kt*32 + kg*8 + j) * HD + ct*16 + row]);
    int node0 = tile * 16;
    const u16* ar = A + (size_t)(node0 + row) * HD + kg * 8;
    short8v af0 = *(const short8v*)(ar);
    short8v af1 = *(const short8v*)(ar + 32);
    accf4 acc[4] = {};
    #pragma unroll
    for (int ct = 0; ct < 4; ct++) {
        acc[ct] = __builtin_amdgcn_mfma_f32_16x16x32_bf16(af0, bW[0][ct], acc[ct], 0, 0, 0);
        acc[ct] = __builtin_amdgcn_mfma_f32_16x16x32_bf16(af1, bW[1][ct], acc[ct], 0, 0, 0);
    }
    float dr[4];
    #pragma unroll
    for (int r = 0; r < 4; r++) dr[r] = dinv[node0 + kg*4 + r];
    #pragma unroll
    for (int ct = 0; ct < 4; ct++)
        #pragma unroll
        for (int r = 0; r < 4; r++)
            out[(size_t)(node0 + kg*4 + r) * HD + ct*16 + row] = f2b(acc[ct][r] * dr[r]);
}

// ---- fused agg(conv1, bf16 gather) + mm64(conv2): tbl2 written as fp8 e4m3 ----
__launch_bounds__(256)
__global__ void k_aggmm(const uint4* __restrict__ Bm4, const int* __restrict__ off,
                        const uint2* __restrict__ csr, const float* __restrict__ dinv,
                        const float* __restrict__ bias, const float* __restrict__ W2,
                        unsigned char* __restrict__ tbl2) {
    __shared__ u32 hs[32 * HSTR];            // 32 h1-rows, stride 72 bf16
    int lane = threadIdx.x & 63;
    int wave = threadIdx.x >> 6;
    int g    = lane >> 3;
    int fp   = lane & 7;
    int node = blockIdx.x * 32 + wave * 8 + g;
    int s = off[node], e = off[node + 1];
    int deg = e - s;
    float di = dinv[node];
    uint4 sw = Bm4[(size_t)node * 8 + fp];
    float a0 = u2lo(sw.x), a1 = u2hi(sw.x), a2 = u2lo(sw.y), a3 = u2hi(sw.y);
    float a4 = u2lo(sw.z), a5 = u2hi(sw.z), a6 = u2lo(sw.w), a7 = u2hi(sw.w);
    uint2 c0 = csr[s+0], c1 = csr[s+1], c2 = csr[s+2], c3 = csr[s+3];
    for (int j = 0; __any(j < deg); j += 4) {
        uint2 n0 = csr[s+j+4], n1 = csr[s+j+5], n2 = csr[s+j+6], n3 = csr[s+j+7];
        bool b0 = (j+0) < deg; u32 r0 = b0 ? c0.x : (u32)node; float w0 = b0 ? __uint_as_float(c0.y) : 0.f;
        bool b1 = (j+1) < deg; u32 r1 = b1 ? c1.x : (u32)node; float w1 = b1 ? __uint_as_float(c1.y) : 0.f;
        bool b2 = (j+2) < deg; u32 r2 = b2 ? c2.x : (u32)node; float w2 = b2 ? __uint_as_float(c2.y) : 0.f;
        bool b3 = (j+3) < deg; u32 r3 = b3 ? c3.x : (u32)node; float w3 = b3 ? __uint_as_float(c3.y) : 0.f;
        uint4 g0 = Bm4[(size_t)r0 * 8 + fp];
        uint4 g1 = Bm4[(size_t)r1 * 8 + fp];
        uint4 g2 = Bm4[(size_t)r2 * 8 + fp];
        uint4 g3 = Bm4[(size_t)r3 * 8 + fp];
        a0 += w0*u2lo(g0.x) + w1*u2lo(g1.x) + w2*u2lo(g2.x) + w3*u2lo(g3.x);
        a1 += w0*u2hi(g0.x) + w1*u2hi(g1.x) + w2*u2hi(g2.x) + w3*u2hi(g3.x);
        a2 += w0*u2lo(g0.y) + w1*u2lo(g1.y) + w2*u2lo(g2.y) + w3*u2lo(g3.y);
        a3 += w0*u2hi(g0.y) + w1*u2hi(g1.y) + w2*u2hi(g2.y) + w3*u2hi(g3.y);
        a4 += w0*u2lo(g0.z) + w1*u2lo(g1.z) + w2*u2lo(g2.z) + w3*u2lo(g3.z);
        a5 += w0*u2hi(g0.z) + w1*u2hi(g1.z) + w2*u2hi(g2.z) + w3*u2hi(g3.z);
        a6 += w0*u2lo(g0.w) + w1*u2lo(g1.w) + w2*u2lo(g2.w) + w3*u2lo(g3.w);
        a7 += w0*u2hi(g0.w) + w1*u2hi(g1.w) + w2*u2hi(g2.w) + w3*u2hi(g3.w);
        c0 = n0; c1 = n1; c2 = n2; c3 = n3;
    }
    float4 blo = *(const float4*)(bias + fp * 8);
    float4 bhi = *(const float4*)(bias + fp * 8 + 4);
    int lrow = wave * 8 + g;
    uint4 hv;
    hv.x = pk2(fmaxf(di*a0 + blo.x, 0.f), fmaxf(di*a1 + blo.y, 0.f));
    hv.y = pk2(fmaxf(di*a2 + blo.z, 0.f), fmaxf(di*a3 + blo.w, 0.f));
    hv.z = pk2(fmaxf(di*a4 + bhi.x, 0.f), fmaxf(di*a5 + bhi.y, 0.f));
    hv.w = pk2(fmaxf(di*a6 + bhi.z, 0.f), fmaxf(di*a7 + bhi.w, 0.f));
    *(uint4*)(hs + lrow * HSTR + fp * 4) = hv;
    __syncthreads();
    // mm64 phase: wave w -> tile t=w&1 (16 rows), col-tiles ctbase..ctbase+1
    int row = lane & 15;
    int kg  = lane >> 4;
    int t      = wave & 1;
    int ctbase = (wave >> 1) * 2;
    short8v bW[2][2];
    #pragma unroll
    for (int kt = 0; kt < 2; kt++)
        #pragma unroll
        for (int cc = 0; cc < 2; cc++)
            #pragma unroll
            for (int j = 0; j < 8; j++)
                bW[kt][cc][j] = (short)f2b(W2[(kt*32 + kg*8 + j) * HD + (ctbase+cc)*16 + row]);
    short8v af0 = *(const short8v*)(hs + (t*16 + row) * HSTR + kg * 4);
    short8v af1 = *(const short8v*)(hs + (t*16 + row) * HSTR + 16 + kg * 4);
    accf4 acc[2] = {};
    #pragma unroll
    for (int cc = 0; cc < 2; cc++) {
        acc[cc] = __builtin_amdgcn_mfma_f32_16x16x32_bf16(af0, bW[0][cc], acc[cc], 0, 0, 0);
        acc[cc] = __builtin_amdgcn_mfma_f32_16x16x32_bf16(af1, bW[1][cc], acc[cc], 0, 0, 0);
    }
    int node0 = blockIdx.x * 32 + t * 16;
    float dr[4];
    #pragma unroll
    for (int r = 0; r < 4; r++) dr[r] = dinv[node0 + kg*4 + r];
    #pragma unroll
    for (int cc = 0; cc < 2; cc++)
        #pragma unroll
        for (int r = 0; r < 4; r++)
            tbl2[(size_t)(node0 + kg*4 + r) * HD + (ctbase+cc)*16 + row] = f2fp8(acc[cc][r] * dr[r]);
}

// ---- fused agg(conv2, fp8 gather) + lin2 + log_softmax ----
__launch_bounds__(256)
__global__ void k_aggout(const uint2* __restrict__ T8, const int* __restrict__ off,
                         const uint2* __restrict__ csr, const float* __restrict__ dinv,
                         const float* __restrict__ bias, const float* __restrict__ Wo,
                         const float* __restrict__ bo, float* __restrict__ outp) {
    __shared__ u32 hs[32 * HSTR];
    int lane = threadIdx.x & 63;
    int wave = threadIdx.x >> 6;
    int g    = lane >> 3;
    int fp   = lane & 7;
    int node = blockIdx.x * 32 + wave * 8 + g;
    int s = off[node], e = off[node + 1];
    int deg = e - s;
    float di = dinv[node];
    float a0, a1, a2, a3, a4, a5, a6, a7;
    {
        uint2 sw = T8[(size_t)node * 8 + fp];      // 8 fp8 of own row
        f32x2 p0 = __builtin_amdgcn_cvt_pk_f32_fp8(sw.x, false);
        f32x2 p1 = __builtin_amdgcn_cvt_pk_f32_fp8(sw.x, true);
        f32x2 p2 = __builtin_amdgcn_cvt_pk_f32_fp8(sw.y, false);
        f32x2 p3 = __builtin_amdgcn_cvt_pk_f32_fp8(sw.y, true);
        a0 = p0[0]; a1 = p0[1]; a2 = p1[0]; a3 = p1[1];
        a4 = p2[0]; a5 = p2[1]; a6 = p3[0]; a7 = p3[1];
    }
    uint2 c0 = csr[s+0], c1 = csr[s+1], c2 = csr[s+2], c3 = csr[s+3];
    for (int j = 0; __any(j < deg); j += 4) {
        uint2 n0 = csr[s+j+4], n1 = csr[s+j+5], n2 = csr[s+j+6], n3 = csr[s+j+7];
        bool b0 = (j+0) < deg; u32 r0 = b0 ? c0.x : (u32)node; float w0 = b0 ? __uint_as_float(c0.y) : 0.f;
        bool b1 = (j+1) < deg; u32 r1 = b1 ? c1.x : (u32)node; float w1 = b1 ? __uint_as_float(c1.y) : 0.f;
        bool b2 = (j+2) < deg; u32 r2 = b2 ? c2.x : (u32)node; float w2 = b2 ? __uint_as_float(c2.y) : 0.f;
        bool b3 = (j+3) < deg; u32 r3 = b3 ? c3.x : (u32)node; float w3 = b3 ? __uint_as_float(c3.y) : 0.f;
        uint2 g0 = T8[(size_t)r0 * 8 + fp];
        uint2 g1 = T8[(size_t)r1 * 8 + fp];
        uint2 g2 = T8[(size_t)r2 * 8 + fp];
        uint2 g3 = T8[(size_t)r3 * 8 + fp];
        #pragma unroll
        for (int q = 0; q < 4; q++) {
            u32 lox = (q == 0) ? g0.x : (q == 1) ? g1.x : (q == 2) ? g2.x : g3.x;
            u32 loy = (q == 0) ? g0.y : (q == 1) ? g1.y : (q == 2) ? g2.y : g3.y;
            float wq = (q == 0) ? w0 : (q == 1) ? w1 : (q == 2) ? w2 : w3;
            f32x2 p0 = __builtin_amdgcn_cvt_pk_f32_fp8(lox, false);
            f32x2 p1 = __builtin_amdgcn_cvt_pk_f32_fp8(lox, true);
            f32x2 p2 = __builtin_amdgcn_cvt_pk_f32_fp8(loy, false);
            f32x2 p3 = __builtin_amdgcn_cvt_pk_f32_fp8(loy, true);
            a0 += wq * p0[0]; a1 += wq * p0[1];
            a2 += wq * p1[0]; a3 += wq * p1[1];
            a4 += wq * p2[0]; a5 += wq * p2[1];
            a6 += wq * p3[0]; a7 += wq * p3[1];
        }
        c0 = n0; c1 = n1; c2 = n2; c3 = n3;
    }
    float4 blo = *(const float4*)(bias + fp * 8);
    float4 bhi = *(const float4*)(bias + fp * 8 + 4);
    int lrow = wave * 8 + g;
    uint4 hv;
    hv.x = pk2(fmaxf(di*a0 + blo.x, 0.f), fmaxf(di*a1 + blo.y, 0.f));
    hv.y = pk2(fmaxf(di*a2 + blo.z, 0.f), fmaxf(di*a3 + blo.w, 0.f));
    hv.z = pk2(fmaxf(di*a4 + bhi.x, 0.f), fmaxf(di*a5 + bhi.y, 0.f));
    hv.w = pk2(fmaxf(di*a6 + bhi.z, 0.f), fmaxf(di*a7 + bhi.w, 0.f));
    *(uint4*)(hs + lrow * HSTR + fp * 4) = hv;
    __syncthreads();
    if (wave >= 2) return;                   // waves 0,1 each do one 16-row tile
    int row = lane & 15;
    int kg  = lane >> 4;
    int t = wave;
    short8v bW[2][3];
    #pragma unroll
    for (int kt = 0; kt < 2; kt++)
        #pragma unroll
        for (int ct = 0; ct < 3; ct++) {
            int col = ct*16 + row;
            #pragma unroll
            for (int j = 0; j < 8; j++)
                bW[kt][ct][j] = (col < NC) ? (short)f2b(Wo[(kt*32 + kg*8 + j) * NC + col]) : (short)0;
        }
    short8v af0 = *(const short8v*)(hs + (t*16 + row) * HSTR + kg * 4);
    short8v af1 = *(const short8v*)(hs + (t*16 + row) * HSTR + 16 + kg * 4);
    accf4 acc[3] = {};
    #pragma unroll
    for (int ct = 0; ct < 3; ct++) {
        acc[ct] = __builtin_amdgcn_mfma_f32_16x16x32_bf16(af0, bW[0][ct], acc[ct], 0, 0, 0);
        acc[ct] = __builtin_amdgcn_mfma_f32_16x16x32_bf16(af1, bW[1][ct], acc[ct], 0, 0, 0);
    }
    int node0 = blockIdx.x * 32 + t * 16;
    float bias0 = bo[row];
    float bias1 = bo[16 + row];
    bool  has2  = (32 + row) < NC;
    float bias2 = has2 ? bo[32 + row] : 0.f;
    #pragma unroll
    for (int r = 0; r < 4; r++) {
        float l0 = acc[0][r] + bias0;
        float l1 = acc[1][r] + bias1;
        float l2 = has2 ? acc[2][r] + bias2 : -1e30f;
        float m = fmaxf(fmaxf(l0, l1), l2);
        #pragma unroll
        for (int s2 = 8; s2 > 0; s2 >>= 1) m = fmaxf(m, __shfl_xor(m, s2));
        float sum = expf(l0 - m) + expf(l1 - m) + (has2 ? expf(l2 - m) : 0.f);
        #pragma unroll
        for (int s2 = 8; s2 > 0; s2 >>= 1) sum += __shfl_xor(sum, s2);
        float ls = logf(sum);
        size_t base = (size_t)(node0 + kg*4 + r) * NC;
        outp[base + row]      = (l0 - m) - ls;
        outp[base + 16 + row] = (l1 - m) - ls;
        if (has2) outp[base + 32 + row] = (l2 - m) - ls;
    }
}

// ---------------- launch ----------------

extern "C" void kernel_launch(void* const* d_in, const int* in_sizes, int n_in,
                              void* d_out, int out_size, void* d_ws, size_t ws_size,
                              hipStream_t stream) {
    const float* x   = (const float*)d_in[0];
    const int*   ei  = (const int*)  d_in[1];
    const float* ew  = (const float*)d_in[2];
    const float* Wf  = (const float*)d_in[3];
    const float* bf  = (const float*)d_in[4];
    const float* Wc1 = (const float*)d_in[5];
    const float* bc1 = (const float*)d_in[6];
    const float* Wc2 = (const float*)d_in[7];
    const float* bc2 = (const float*)d_in[8];
    const float* Wo  = (const float*)d_in[9];
    const float* bo  = (const float*)d_in[10];
    float* out = (float*)d_out;

    char* w = (char*)d_ws;
    auto alloc = [&](size_t bytes) {
        char* p = w;
        w += (bytes + 511) & ~(size_t)511;
        return p;
    };
    u32*   hist = (u32*)  alloc((size_t)NBLK * NBUK * 4);
    u32*   btot = (u32*)  alloc((size_t)NBUK * 4);
    u32*   bst  = (u32*)  alloc((size_t)(NBUK + 1) * 4);
    float* dinv = (float*)alloc((size_t)NN * 4);
    int*   off  = (int*)  alloc((size_t)(NN + 1) * 4);
    uint2* rec  = (uint2*)alloc((size_t)NE * 8);
    uint2* csr  = (uint2*)alloc((size_t)(NE + 128) * 8);  // +128 pad for over-read
    u16*   hA   = (u16*)  alloc((size_t)NN * HD * 2);     // bf16 h1 / fp8 tbl2 host buffer
    u16*   hB   = (u16*)  alloc((size_t)NN * HD * 2);     // bf16 tbl1

    k_build1 <<<NBLK + MM_BLOCKS, 256, 0, stream>>>(ei, hist, x, Wf, bf, hA);
    k_bscan  <<<NBUK, 64, 0, stream>>>(hist, btot);
    k_bstart <<<1, 64, 0, stream>>>(btot, bst, off);
    k_scatter<<<NBLK, 256, 0, stream>>>(ei, ew, hist, bst, rec);
    k_bucket <<<NBUK, 256, 0, stream>>>(rec, bst, dinv, off, csr);

    k_mm64  <<<MM_BLOCKS, 256, 0, stream>>>(hA, Wc1, dinv, hB);                 // tbl1 (bf16)
    k_aggmm <<<NN / 32, 256, 0, stream>>>((const uint4*)hB, off, csr, dinv, bc1, Wc2,
                                          (unsigned char*)hA);                  // tbl2 (fp8)
    k_aggout<<<NN / 32, 256, 0, stream>>>((const uint2*)hA, off, csr, dinv, bc2, Wo, bo, out);
}

// Round 16
// 155.353 us; speedup vs baseline: 1.2002x; 1.0512x over previous
//
#include <hip/hip_runtime.h>
#include <hip/hip_bf16.h>
#include <cstdint>
#include <cstddef>

#define NN 100000
#define NE 1600000
#define FIN 128
#define HD 64
#define NC 40
#define NTILE (NN / 16)                      // 6250 MFMA row-tiles
#define MM_BLOCKS ((NTILE + 3) / 4)          // 1563

#define BUK 256                              // nodes per bucket
#define NBUK ((NN + BUK - 1) / BUK)          // 391
#define EPB 1024                             // edges per hist/scatter block
#define NBLK ((NE + EPB - 1) / EPB)          // 1563

#define XSTR 68                              // build1 LDS row stride in u32
#define HSTR 36                              // agg-epilogue LDS row stride in u32 (72 bf16)

typedef unsigned short u16;
typedef unsigned int u32;
typedef __attribute__((ext_vector_type(8))) short short8v;
typedef __attribute__((ext_vector_type(4))) float accf4;
typedef __attribute__((ext_vector_type(2))) float f32x2;

__device__ __forceinline__ float u2lo(u32 u) { return __uint_as_float(u << 16); }
__device__ __forceinline__ float u2hi(u32 u) { return __uint_as_float(u & 0xFFFF0000u); }
__device__ __forceinline__ u16 f2b(float f) {            // RNE f32->bf16
    u32 u = __float_as_uint(f);
    return (u16)((u + 0x7FFFu + ((u >> 16) & 1u)) >> 16);
}
__device__ __forceinline__ u32 pk2(float lo, float hi) {
    return (u32)f2b(lo) | ((u32)f2b(hi) << 16);
}
__device__ __forceinline__ unsigned char f2fp8(float v) {   // f32 -> fp8 e4m3 (OCP)
    int r = __builtin_amdgcn_cvt_pk_fp8_f32(v, 0.f, 0, false);
    return (unsigned char)(r & 0xFF);
}

// ------- fused: per-block bucket histogram (LDS) || lin1 (LDS-staged x + MFMA) -------
__launch_bounds__(256)
__global__ void k_build1(const int* __restrict__ ei, u32* __restrict__ hist,
                         const float* __restrict__ x, const float* __restrict__ W,
                         const float* __restrict__ b, u16* __restrict__ out) {
    if (blockIdx.x < NBLK) {
        __shared__ u32 lh[NBUK];
        int blk = blockIdx.x, tid = threadIdx.x;
        for (int i = tid; i < NBUK; i += 256) lh[i] = 0;
        __syncthreads();
        #pragma unroll
        for (int it = 0; it < EPB / 256; it++) {
            int e = blk * EPB + it * 256 + tid;
            if (e < NE) {
                int col = ei[NE + e];
                atomicAdd(&lh[col >> 8], 1u);
            }
        }
        __syncthreads();
        for (int i = tid; i < NBUK; i += 256)
            hist[(size_t)blk * NBUK + i] = lh[i];      // transposed: coalesced write
        return;
    }
    // ---- lin1 half: stage 64 x-rows as bf16 in LDS (coalesced), then MFMA ----
    __shared__ u32 xs[64 * XSTR];
    int tid = threadIdx.x;
    int bi  = blockIdx.x - NBLK;
    int nodeB = bi * 64;
    const float4* x4 = (const float4*)x;
    for (int idx = tid; idx < 64 * 16; idx += 256) {
        int row = idx >> 4, seg = idx & 15;
        uint4 d = make_uint4(0u, 0u, 0u, 0u);
        if (nodeB + row < NN) {
            float4 a = x4[(size_t)(nodeB + row) * 32 + seg * 2];
            float4 c = x4[(size_t)(nodeB + row) * 32 + seg * 2 + 1];
            d.x = pk2(a.x, a.y);
            d.y = pk2(a.z, a.w);
            d.z = pk2(c.x, c.y);
            d.w = pk2(c.z, c.w);
        }
        *(uint4*)(xs + row * XSTR + seg * 4) = d;
    }
    __syncthreads();
    int lane = tid & 63;
    int wv   = tid >> 6;
    int tile = bi * 4 + wv;
    if (tile >= NTILE) return;
    int row = lane & 15;
    int kg  = lane >> 4;
    short8v bW[4][4];
    #pragma unroll
    for (int kt = 0; kt < 4; kt++)
        #pragma unroll
        for (int ct = 0; ct < 4; ct++)
            #pragma unroll
            for (int j = 0; j < 8; j++)
                bW[kt][ct][j] = (short)f2b(W[(kt*32 + kg*8 + j) * HD + ct*16 + row]);
    int node0 = tile * 16;
    short8v af[4];
    #pragma unroll
    for (int kt = 0; kt < 4; kt++)
        af[kt] = *(const short8v*)(xs + (wv*16 + row) * XSTR + kt * 16 + kg * 4);
    accf4 acc[4] = {};
    #pragma unroll
    for (int kt = 0; kt < 4; kt++)
        #pragma unroll
        for (int ct = 0; ct < 4; ct++)
            acc[ct] = __builtin_amdgcn_mfma_f32_16x16x32_bf16(af[kt], bW[kt][ct], acc[ct], 0, 0, 0);
    #pragma unroll
    for (int ct = 0; ct < 4; ct++) {
        float bias = b[ct*16 + row];
        #pragma unroll
        for (int r = 0; r < 4; r++) {
            float v = fmaxf(acc[ct][r] + bias, 0.f);
            out[(size_t)(node0 + kg*4 + r) * HD + ct*16 + row] = f2b(v);
        }
    }
}

// per-bucket exclusive prefix over blocks (in place, transposed layout); total -> bucketTotal
__global__ void k_bscan(u32* __restrict__ hist, u32* __restrict__ bucketTotal) {
    int b = blockIdx.x;
    int lane = threadIdx.x;                  // 64 threads
    u32 carry = 0;
    for (int j0 = 0; j0 < NBLK; j0 += 64) {
        int j = j0 + lane;
        u32 v = (j < NBLK) ? hist[(size_t)j * NBUK + b] : 0;
        u32 inc = v;
        #pragma unroll
        for (int d = 1; d < 64; d <<= 1) {
            u32 t = __shfl_up(inc, d);
            if (lane >= d) inc += t;
        }
        if (j < NBLK) hist[(size_t)j * NBUK + b] = carry + inc - v;
        carry += __shfl(inc, 63);
    }
    if (lane == 0) bucketTotal[b] = carry;
}

// scan bucketTotal -> bucketStart (exclusive); bucketStart[NBUK]=NE; off[NN]=NE
__global__ void k_bstart(const u32* __restrict__ bucketTotal, u32* __restrict__ bucketStart,
                         int* __restrict__ off) {
    int lane = threadIdx.x;                  // 64 threads
    u32 carry = 0;
    for (int j0 = 0; j0 < NBUK; j0 += 64) {
        int j = j0 + lane;
        u32 v = (j < NBUK) ? bucketTotal[j] : 0;
        u32 inc = v;
        #pragma unroll
        for (int d = 1; d < 64; d <<= 1) {
            u32 t = __shfl_up(inc, d);
            if (lane >= d) inc += t;
        }
        if (j < NBUK) bucketStart[j] = carry + inc - v;
        carry += __shfl(inc, 63);
    }
    if (lane == 0) { bucketStart[NBUK] = carry; off[NN] = (int)carry; }
}

// scatter edges into bucket segments: rank via LDS atomics; one packed 8B record
// rec.x = row | (in-bucket col << 24), rec.y = raw ew bits
__launch_bounds__(256)
__global__ void k_scatter(const int* __restrict__ ei, const float* __restrict__ ew,
                          const u32* __restrict__ hist, const u32* __restrict__ bucketStart,
                          uint2* __restrict__ rec) {
    __shared__ u32 lh[NBUK];
    __shared__ u32 gb[NBUK];
    int blk = blockIdx.x, tid = threadIdx.x;
    for (int i = tid; i < NBUK; i += 256) {
        lh[i] = 0;
        gb[i] = bucketStart[i] + hist[(size_t)blk * NBUK + i];   // coalesced
    }
    __syncthreads();
    #pragma unroll
    for (int it = 0; it < EPB / 256; it++) {
        int e = blk * EPB + it * 256 + tid;
        if (e < NE) {
            int row = ei[e], col = ei[NE + e];
            float wv = ew[e];
            int bkt = col >> 8;
            u32 cl = (u32)(col & 255);
            u32 r = atomicAdd(&lh[bkt], 1u);
            u32 slot = gb[bkt] + r;
            rec[slot] = make_uint2((u32)row | (cl << 24), __float_as_uint(wv));
        }
    }
}

// per-bucket CSR build: packed LDS hist -> dinv, off, csr=(row, raw ew)
__launch_bounds__(256)
__global__ void k_bucket(const uint2* __restrict__ rec, const u32* __restrict__ bucketStart,
                         float* __restrict__ dinv, int* __restrict__ off,
                         uint2* __restrict__ csr) {
    __shared__ u32 lpk[BUK];
    __shared__ u32 loff[BUK];
    __shared__ u32 wt[4];
    int b = blockIdx.x, tid = threadIdx.x;
    int base = b * BUK;
    u32 seg0 = bucketStart[b], seg1 = bucketStart[b + 1];
    int nb = (int)(seg1 - seg0);
    lpk[tid] = 0;
    __syncthreads();
    for (int idx = tid; idx < nb; idx += 256) {
        uint2 ab = rec[seg0 + idx];
        u32 cl = ab.x >> 24;
        u32 fx = __float2uint_rn(__uint_as_float(ab.y) * 16384.0f);   // Q6.14
        atomicAdd(&lpk[cl], (1u << 20) | fx);
    }
    __syncthreads();
    u32 pk = lpk[tid];
    u32 cnt = pk >> 20;
    int node = base + tid;
    if (node < NN) dinv[node] = rsqrtf(1.0f + (float)(pk & 0xFFFFFu) * (1.0f / 16384.0f));
    int lane = tid & 63, wid = tid >> 6;
    u32 inc = cnt;
    #pragma unroll
    for (int d = 1; d < 64; d <<= 1) {
        u32 t = __shfl_up(inc, d);
        if (lane >= d) inc += t;
    }
    if (lane == 63) wt[wid] = inc;
    __syncthreads();
    u32 wof = 0;
    #pragma unroll
    for (int k = 0; k < 4; k++) if (k < wid) wof += wt[k];
    loff[tid] = wof + inc - cnt;
    if (node < NN) off[node] = (int)(seg0 + loff[tid]);
    lpk[tid] = 0;                    // reuse as rank counters
    __syncthreads();
    for (int idx = tid; idx < nb; idx += 256) {
        uint2 ab = rec[seg0 + idx];
        u32 cl = ab.x >> 24;
        u32 r2 = atomicAdd(&lpk[cl], 1u);
        csr[seg0 + loff[cl] + r2] = make_uint2(ab.x & 0xFFFFFFu, ab.y);   // (row, raw ew)
    }
}

// tbl1(fp8) = dinv-scaled A(bf16) @ W: tbl'[r] = dinv[r] * (A@W)[r]
__launch_bounds__(256)
__global__ void k_mm64(const u16* __restrict__ A, const float* __restrict__ W,
                       const float* __restrict__ dinv, unsigned char* __restrict__ out) {
    int lane = threadIdx.x & 63;
    int tile = blockIdx.x * 4 + (threadIdx.x >> 6);
    if (tile >= NTILE) return;
    int row = lane & 15;
    int kg  = lane >> 4;
    short8v bW[2][4];
    #pragma unroll
    for (int kt = 0; kt < 2; kt++)
        #pragma unroll
        for (int ct = 0; ct < 4; ct++)
            #pragma unroll
            for (int j = 0; j < 8; j++)
                bW[kt][ct][j] = (short)f2b(W[(kt*32 + kg*8 + j) * HD + ct*16 + row]);
    int node0 = tile * 16;
    const u16* ar = A + (size_t)(node0 + row) * HD + kg * 8;
    short8v af0 = *(const short8v*)(ar);
    short8v af1 = *(const short8v*)(ar + 32);
    accf4 acc[4] = {};
    #pragma unroll
    for (int ct = 0; ct < 4; ct++) {
        acc[ct] = __builtin_amdgcn_mfma_f32_16x16x32_bf16(af0, bW[0][ct], acc[ct], 0, 0, 0);
        acc[ct] = __builtin_amdgcn_mfma_f32_16x16x32_bf16(af1, bW[1][ct], acc[ct], 0, 0, 0);
    }
    float dr[4];
    #pragma unroll
    for (int r = 0; r < 4; r++) dr[r] = dinv[node0 + kg*4 + r];
    #pragma unroll
    for (int ct = 0; ct < 4; ct++)
        #pragma unroll
        for (int r = 0; r < 4; r++)
            out[(size_t)(node0 + kg*4 + r) * HD + ct*16 + row] = f2fp8(acc[ct][r] * dr[r]);
}

// ---- fused agg(conv1, fp8 gather) + mm64(conv2): tbl2 written as fp8 e4m3 ----
__launch_bounds__(256)
__global__ void k_aggmm(const uint2* __restrict__ T8, const int* __restrict__ off,
                        const uint2* __restrict__ csr, const float* __restrict__ dinv,
                        const float* __restrict__ bias, const float* __restrict__ W2,
                        unsigned char* __restrict__ tbl2) {
    __shared__ u32 hs[32 * HSTR];            // 32 h1-rows, stride 72 bf16
    int lane = threadIdx.x & 63;
    int wave = threadIdx.x >> 6;
    int g    = lane >> 3;
    int fp   = lane & 7;
    int node = blockIdx.x * 32 + wave * 8 + g;
    int s = off[node], e = off[node + 1];
    int deg = e - s;
    float di = dinv[node];
    float a0, a1, a2, a3, a4, a5, a6, a7;
    {
        uint2 sw = T8[(size_t)node * 8 + fp];      // 8 fp8 of own row
        f32x2 p0 = __builtin_amdgcn_cvt_pk_f32_fp8(sw.x, false);
        f32x2 p1 = __builtin_amdgcn_cvt_pk_f32_fp8(sw.x, true);
        f32x2 p2 = __builtin_amdgcn_cvt_pk_f32_fp8(sw.y, false);
        f32x2 p3 = __builtin_amdgcn_cvt_pk_f32_fp8(sw.y, true);
        a0 = p0[0]; a1 = p0[1]; a2 = p1[0]; a3 = p1[1];
        a4 = p2[0]; a5 = p2[1]; a6 = p3[0]; a7 = p3[1];
    }
    uint2 c0 = csr[s+0], c1 = csr[s+1], c2 = csr[s+2], c3 = csr[s+3];
    for (int j = 0; __any(j < deg); j += 4) {
        uint2 n0 = csr[s+j+4], n1 = csr[s+j+5], n2 = csr[s+j+6], n3 = csr[s+j+7];
        bool b0 = (j+0) < deg; u32 r0 = b0 ? c0.x : (u32)node; float w0 = b0 ? __uint_as_float(c0.y) : 0.f;
        bool b1 = (j+1) < deg; u32 r1 = b1 ? c1.x : (u32)node; float w1 = b1 ? __uint_as_float(c1.y) : 0.f;
        bool b2 = (j+2) < deg; u32 r2 = b2 ? c2.x : (u32)node; float w2 = b2 ? __uint_as_float(c2.y) : 0.f;
        bool b3 = (j+3) < deg; u32 r3 = b3 ? c3.x : (u32)node; float w3 = b3 ? __uint_as_float(c3.y) : 0.f;
        uint2 g0 = T8[(size_t)r0 * 8 + fp];
        uint2 g1 = T8[(size_t)r1 * 8 + fp];
        uint2 g2 = T8[(size_t)r2 * 8 + fp];
        uint2 g3 = T8[(size_t)r3 * 8 + fp];
        #pragma unroll
        for (int q = 0; q < 4; q++) {
            u32 lox = (q == 0) ? g0.x : (q == 1) ? g1.x : (q == 2) ? g2.x : g3.x;
            u32 loy = (q == 0) ? g0.y : (q == 1) ? g1.y : (q == 2) ? g2.y : g3.y;
            float wq = (q == 0) ? w0 : (q == 1) ? w1 : (q == 2) ? w2 : w3;
            f32x2 p0 = __builtin_amdgcn_cvt_pk_f32_fp8(lox, false);
            f32x2 p1 = __builtin_amdgcn_cvt_pk_f32_fp8(lox, true);
            f32x2 p2 = __builtin_amdgcn_cvt_pk_f32_fp8(loy, false);
            f32x2 p3 = __builtin_amdgcn_cvt_pk_f32_fp8(loy, true);
            a0 += wq * p0[0]; a1 += wq * p0[1];
            a2 += wq * p1[0]; a3 += wq * p1[1];
            a4 += wq * p2[0]; a5 += wq * p2[1];
            a6 += wq * p3[0]; a7 += wq * p3[1];
        }
        c0 = n0; c1 = n1; c2 = n2; c3 = n3;
    }
    float4 blo = *(const float4*)(bias + fp * 8);
    float4 bhi = *(const float4*)(bias + fp * 8 + 4);
    int lrow = wave * 8 + g;
    uint4 hv;
    hv.x = pk2(fmaxf(di*a0 + blo.x, 0.f), fmaxf(di*a1 + blo.y, 0.f));
    hv.y = pk2(fmaxf(di*a2 + blo.z, 0.f), fmaxf(di*a3 + blo.w, 0.f));
    hv.z = pk2(fmaxf(di*a4 + bhi.x, 0.f), fmaxf(di*a5 + bhi.y, 0.f));
    hv.w = pk2(fmaxf(di*a6 + bhi.z, 0.f), fmaxf(di*a7 + bhi.w, 0.f));
    *(uint4*)(hs + lrow * HSTR + fp * 4) = hv;
    __syncthreads();
    // mm64 phase: wave w -> tile t=w&1 (16 rows), col-tiles ctbase..ctbase+1
    int row = lane & 15;
    int kg  = lane >> 4;
    int t      = wave & 1;
    int ctbase = (wave >> 1) * 2;
    short8v bW[2][2];
    #pragma unroll
    for (int kt = 0; kt < 2; kt++)
        #pragma unroll
        for (int cc = 0; cc < 2; cc++)
            #pragma unroll
            for (int j = 0; j < 8; j++)
                bW[kt][cc][j] = (short)f2b(W2[(kt*32 + kg*8 + j) * HD + (ctbase+cc)*16 + row]);
    short8v af0 = *(const short8v*)(hs + (t*16 + row) * HSTR + kg * 4);
    short8v af1 = *(const short8v*)(hs + (t*16 + row) * HSTR + 16 + kg * 4);
    accf4 acc[2] = {};
    #pragma unroll
    for (int cc = 0; cc < 2; cc++) {
        acc[cc] = __builtin_amdgcn_mfma_f32_16x16x32_bf16(af0, bW[0][cc], acc[cc], 0, 0, 0);
        acc[cc] = __builtin_amdgcn_mfma_f32_16x16x32_bf16(af1, bW[1][cc], acc[cc], 0, 0, 0);
    }
    int node0 = blockIdx.x * 32 + t * 16;
    float dr[4];
    #pragma unroll
    for (int r = 0; r < 4; r++) dr[r] = dinv[node0 + kg*4 + r];
    #pragma unroll
    for (int cc = 0; cc < 2; cc++)
        #pragma unroll
        for (int r = 0; r < 4; r++)
            tbl2[(size_t)(node0 + kg*4 + r) * HD + (ctbase+cc)*16 + row] = f2fp8(acc[cc][r] * dr[r]);
}

// ---- fused agg(conv2, fp8 gather) + lin2 + log_softmax ----
__launch_bounds__(256)
__global__ void k_aggout(const uint2* __restrict__ T8, const int* __restrict__ off,
                         const uint2* __restrict__ csr, const float* __restrict__ dinv,
                         const float* __restrict__ bias, const float* __restrict__ Wo,
                         const float* __restrict__ bo, float* __restrict__ outp) {
    __shared__ u32 hs[32 * HSTR];
    int lane = threadIdx.x & 63;
    int wave = threadIdx.x >> 6;
    int g    = lane >> 3;
    int fp   = lane & 7;
    int node = blockIdx.x * 32 + wave * 8 + g;
    int s = off[node], e = off[node + 1];
    int deg = e - s;
    float di = dinv[node];
    float a0, a1, a2, a3, a4, a5, a6, a7;
    {
        uint2 sw = T8[(size_t)node * 8 + fp];      // 8 fp8 of own row
        f32x2 p0 = __builtin_amdgcn_cvt_pk_f32_fp8(sw.x, false);
        f32x2 p1 = __builtin_amdgcn_cvt_pk_f32_fp8(sw.x, true);
        f32x2 p2 = __builtin_amdgcn_cvt_pk_f32_fp8(sw.y, false);
        f32x2 p3 = __builtin_amdgcn_cvt_pk_f32_fp8(sw.y, true);
        a0 = p0[0]; a1 = p0[1]; a2 = p1[0]; a3 = p1[1];
        a4 = p2[0]; a5 = p2[1]; a6 = p3[0]; a7 = p3[1];
    }
    uint2 c0 = csr[s+0], c1 = csr[s+1], c2 = csr[s+2], c3 = csr[s+3];
    for (int j = 0; __any(j < deg); j += 4) {
        uint2 n0 = csr[s+j+4], n1 = csr[s+j+5], n2 = csr[s+j+6], n3 = csr[s+j+7];
        bool b0 = (j+0) < deg; u32 r0 = b0 ? c0.x : (u32)node; float w0 = b0 ? __uint_as_float(c0.y) : 0.f;
        bool b1 = (j+1) < deg; u32 r1 = b1 ? c1.x : (u32)node; float w1 = b1 ? __uint_as_float(c1.y) : 0.f;
        bool b2 = (j+2) < deg; u32 r2 = b2 ? c2.x : (u32)node; float w2 = b2 ? __uint_as_float(c2.y) : 0.f;
        bool b3 = (j+3) < deg; u32 r3 = b3 ? c3.x : (u32)node; float w3 = b3 ? __uint_as_float(c3.y) : 0.f;
        uint2 g0 = T8[(size_t)r0 * 8 + fp];
        uint2 g1 = T8[(size_t)r1 * 8 + fp];
        uint2 g2 = T8[(size_t)r2 * 8 + fp];
        uint2 g3 = T8[(size_t)r3 * 8 + fp];
        #pragma unroll
        for (int q = 0; q < 4; q++) {
            u32 lox = (q == 0) ? g0.x : (q == 1) ? g1.x : (q == 2) ? g2.x : g3.x;
            u32 loy = (q == 0) ? g0.y : (q == 1) ? g1.y : (q == 2) ? g2.y : g3.y;
            float wq = (q == 0) ? w0 : (q == 1) ? w1 : (q == 2) ? w2 : w3;
            f32x2 p0 = __builtin_amdgcn_cvt_pk_f32_fp8(lox, false);
            f32x2 p1 = __builtin_amdgcn_cvt_pk_f32_fp8(lox, true);
            f32x2 p2 = __builtin_amdgcn_cvt_pk_f32_fp8(loy, false);
            f32x2 p3 = __builtin_amdgcn_cvt_pk_f32_fp8(loy, true);
            a0 += wq * p0[0]; a1 += wq * p0[1];
            a2 += wq * p1[0]; a3 += wq * p1[1];
            a4 += wq * p2[0]; a5 += wq * p2[1];
            a6 += wq * p3[0]; a7 += wq * p3[1];
        }
        c0 = n0; c1 = n1; c2 = n2; c3 = n3;
    }
    float4 blo = *(const float4*)(bias + fp * 8);
    float4 bhi = *(const float4*)(bias + fp * 8 + 4);
    int lrow = wave * 8 + g;
    uint4 hv;
    hv.x = pk2(fmaxf(di*a0 + blo.x, 0.f), fmaxf(di*a1 + blo.y, 0.f));
    hv.y = pk2(fmaxf(di*a2 + blo.z, 0.f), fmaxf(di*a3 + blo.w, 0.f));
    hv.z = pk2(fmaxf(di*a4 + bhi.x, 0.f), fmaxf(di*a5 + bhi.y, 0.f));
    hv.w = pk2(fmaxf(di*a6 + bhi.z, 0.f), fmaxf(di*a7 + bhi.w, 0.f));
    *(uint4*)(hs + lrow * HSTR + fp * 4) = hv;
    __syncthreads();
    if (wave >= 2) return;                   // waves 0,1 each do one 16-row tile
    int row = lane & 15;
    int kg  = lane >> 4;
    int t = wave;
    short8v bW[2][3];
    #pragma unroll
    for (int kt = 0; kt < 2; kt++)
        #pragma unroll
        for (int ct = 0; ct < 3; ct++) {
            int col = ct*16 + row;
            #pragma unroll
            for (int j = 0; j < 8; j++)
                bW[kt][ct][j] = (col < NC) ? (short)f2b(Wo[(kt*32 + kg*8 + j) * NC + col]) : (short)0;
        }
    short8v af0 = *(const short8v*)(hs + (t*16 + row) * HSTR + kg * 4);
    short8v af1 = *(const short8v*)(hs + (t*16 + row) * HSTR + 16 + kg * 4);
    accf4 acc[3] = {};
    #pragma unroll
    for (int ct = 0; ct < 3; ct++) {
        acc[ct] = __builtin_amdgcn_mfma_f32_16x16x32_bf16(af0, bW[0][ct], acc[ct], 0, 0, 0);
        acc[ct] = __builtin_amdgcn_mfma_f32_16x16x32_bf16(af1, bW[1][ct], acc[ct], 0, 0, 0);
    }
    int node0 = blockIdx.x * 32 + t * 16;
    float bias0 = bo[row];
    float bias1 = bo[16 + row];
    bool  has2  = (32 + row) < NC;
    float bias2 = has2 ? bo[32 + row] : 0.f;
    #pragma unroll
    for (int r = 0; r < 4; r++) {
        float l0 = acc[0][r] + bias0;
        float l1 = acc[1][r] + bias1;
        float l2 = has2 ? acc[2][r] + bias2 : -1e30f;
        float m = fmaxf(fmaxf(l0, l1), l2);
        #pragma unroll
        for (int s2 = 8; s2 > 0; s2 >>= 1) m = fmaxf(m, __shfl_xor(m, s2));
        float sum = expf(l0 - m) + expf(l1 - m) + (has2 ? expf(l2 - m) : 0.f);
        #pragma unroll
        for (int s2 = 8; s2 > 0; s2 >>= 1) sum += __shfl_xor(sum, s2);
        float ls = logf(sum);
        size_t base = (size_t)(node0 + kg*4 + r) * NC;
        outp[base + row]      = (l0 - m) - ls;
        outp[base + 16 + row] = (l1 - m) - ls;
        if (has2) outp[base + 32 + row] = (l2 - m) - ls;
    }
}

// ---------------- launch ----------------

extern "C" void kernel_launch(void* const* d_in, const int* in_sizes, int n_in,
                              void* d_out, int out_size, void* d_ws, size_t ws_size,
                              hipStream_t stream) {
    const float* x   = (const float*)d_in[0];
    const int*   ei  = (const int*)  d_in[1];
    const float* ew  = (const float*)d_in[2];
    const float* Wf  = (const float*)d_in[3];
    const float* bf  = (const float*)d_in[4];
    const float* Wc1 = (const float*)d_in[5];
    const float* bc1 = (const float*)d_in[6];
    const float* Wc2 = (const float*)d_in[7];
    const float* bc2 = (const float*)d_in[8];
    const float* Wo  = (const float*)d_in[9];
    const float* bo  = (const float*)d_in[10];
    float* out = (float*)d_out;

    char* w = (char*)d_ws;
    auto alloc = [&](size_t bytes) {
        char* p = w;
        w += (bytes + 511) & ~(size_t)511;
        return p;
    };
    u32*   hist = (u32*)  alloc((size_t)NBLK * NBUK * 4);
    u32*   btot = (u32*)  alloc((size_t)NBUK * 4);
    u32*   bst  = (u32*)  alloc((size_t)(NBUK + 1) * 4);
    float* dinv = (float*)alloc((size_t)NN * 4);
    int*   off  = (int*)  alloc((size_t)(NN + 1) * 4);
    uint2* rec  = (uint2*)alloc((size_t)NE * 8);
    uint2* csr  = (uint2*)alloc((size_t)(NE + 128) * 8);  // +128 pad for over-read
    u16*   hA   = (u16*)  alloc((size_t)NN * HD * 2);     // bf16 h1 / fp8 tbl2
    u16*   hB   = (u16*)  alloc((size_t)NN * HD * 2);     // fp8 tbl1

    k_build1 <<<NBLK + MM_BLOCKS, 256, 0, stream>>>(ei, hist, x, Wf, bf, hA);
    k_bscan  <<<NBUK, 64, 0, stream>>>(hist, btot);
    k_bstart <<<1, 64, 0, stream>>>(btot, bst, off);
    k_scatter<<<NBLK, 256, 0, stream>>>(ei, ew, hist, bst, rec);
    k_bucket <<<NBUK, 256, 0, stream>>>(rec, bst, dinv, off, csr);

    k_mm64  <<<MM_BLOCKS, 256, 0, stream>>>(hA, Wc1, dinv, (unsigned char*)hB); // tbl1 (fp8)
    k_aggmm <<<NN / 32, 256, 0, stream>>>((const uint2*)hB, off, csr, dinv, bc1, Wc2,
                                          (unsigned char*)hA);                  // tbl2 (fp8)
    k_aggout<<<NN / 32, 256, 0, stream>>>((const uint2*)hA, off, csr, dinv, bc2, Wo, bo, out);
}